// Round 1
// baseline (8319.264 us; speedup 1.0000x reference)
//
#include <hip/hip_runtime.h>
#include <math.h>

// Problem constants
#define S_LEN 2048
#define DMODEL 512
#define NROWS 4096   // B*S
#define NHEAD 8
#define HDIM 64

// ---------------- block reduction helpers (256 threads) ----------------
__device__ inline float blockReduceSum256(float v, float* sbuf) {
    #pragma unroll
    for (int o = 32; o > 0; o >>= 1) v += __shfl_down(v, o);
    int wid = threadIdx.x >> 6, lane = threadIdx.x & 63;
    __syncthreads();               // protect sbuf reuse from previous call
    if (lane == 0) sbuf[wid] = v;
    __syncthreads();
    return sbuf[0] + sbuf[1] + sbuf[2] + sbuf[3];
}

__device__ inline float blockReduceMax256(float v, float* sbuf) {
    #pragma unroll
    for (int o = 32; o > 0; o >>= 1) v = fmaxf(v, __shfl_down(v, o));
    int wid = threadIdx.x >> 6, lane = threadIdx.x & 63;
    __syncthreads();
    if (lane == 0) sbuf[wid] = v;
    __syncthreads();
    return fmaxf(fmaxf(sbuf[0], sbuf[1]), fmaxf(sbuf[2], sbuf[3]));
}

// ---------------- LayerNorm: one block per row of 512 ----------------
__global__ __launch_bounds__(256) void ln_kernel(
    const float* __restrict__ x, const float* __restrict__ w,
    const float* __restrict__ b, float* __restrict__ y)
{
    __shared__ float red[8];
    const int row = blockIdx.x;
    const float* xr = x + (size_t)row * DMODEL;
    const int t = threadIdx.x;
    float v0 = xr[t];
    float v1 = xr[t + 256];
    float s  = v0 + v1;
    float sq = v0 * v0 + v1 * v1;
    #pragma unroll
    for (int o = 32; o > 0; o >>= 1) {
        s  += __shfl_down(s, o);
        sq += __shfl_down(sq, o);
    }
    int wid = t >> 6, lane = t & 63;
    if (lane == 0) { red[wid] = s; red[4 + wid] = sq; }
    __syncthreads();
    float mean = (red[0] + red[1] + red[2] + red[3]) * (1.0f / 512.0f);
    float msq  = (red[4] + red[5] + red[6] + red[7]) * (1.0f / 512.0f);
    float var  = msq - mean * mean;
    float rs   = rsqrtf(var + 1e-5f);
    y[(size_t)row * DMODEL + t]       = (v0 - mean) * rs * w[t] + b[t];
    y[(size_t)row * DMODEL + t + 256] = (v1 - mean) * rs * w[t + 256] + b[t + 256];
}

// ---------------- generic tiled fp32 GEMM ----------------
// C[N=4096, Mo] = epilogue( A @ W + bias ), A is (4096, K) row-major.
// Concat mode: if A2 != nullptr, columns [0,512) come from A1, [512,1024) from A2
// (both row-stride `lda`). Epilogue: optional exact GELU, then + R1, + R2.
__global__ __launch_bounds__(256) void gemm_kernel(
    const float* __restrict__ A1, const float* __restrict__ A2, int lda,
    const float* __restrict__ W, const float* __restrict__ bias,
    const float* __restrict__ R1, const float* __restrict__ R2,
    float* __restrict__ C, int K, int Mo, int dogelu)
{
    __shared__ __align__(16) float As[16][68];  // [k][m], padded rows
    __shared__ __align__(16) float Bs[16][64];  // [k][n]
    const int tid  = threadIdx.x;
    const int row0 = blockIdx.y * 64;
    const int col0 = blockIdx.x * 64;
    const int tn = tid & 15, tm = tid >> 4;

    float acc[4][4];
    #pragma unroll
    for (int i = 0; i < 4; ++i)
        #pragma unroll
        for (int j = 0; j < 4; ++j) acc[i][j] = 0.0f;

    const int lm = tid >> 2;          // 0..63  (A tile row)
    const int lk = (tid & 3) << 2;    // 0,4,8,12 (A tile k)
    const int bk = tid >> 4;          // 0..15  (B tile k)
    const int bn = (tid & 15) << 2;   // B tile col*4

    for (int k0 = 0; k0 < K; k0 += 16) {
        // ---- stage A (transposed into As[k][m]) ----
        int kg = k0 + lk;
        const float* src = A1; int col = kg;
        if (A2 != nullptr && kg >= 512) { src = A2; col = kg - 512; }
        float4 av = *(const float4*)(src + (size_t)(row0 + lm) * lda + col);
        As[lk + 0][lm] = av.x;
        As[lk + 1][lm] = av.y;
        As[lk + 2][lm] = av.z;
        As[lk + 3][lm] = av.w;
        // ---- stage B ----
        float4 bv = *(const float4*)(W + (size_t)(k0 + bk) * Mo + col0 + bn);
        *(float4*)&Bs[bk][bn] = bv;
        __syncthreads();
        // ---- compute ----
        #pragma unroll
        for (int kk = 0; kk < 16; ++kk) {
            float4 a = *(const float4*)&As[kk][tm << 2];
            float4 b = *(const float4*)&Bs[kk][tn << 2];
            float ar[4] = {a.x, a.y, a.z, a.w};
            float br[4] = {b.x, b.y, b.z, b.w};
            #pragma unroll
            for (int i = 0; i < 4; ++i)
                #pragma unroll
                for (int j = 0; j < 4; ++j)
                    acc[i][j] = fmaf(ar[i], br[j], acc[i][j]);
        }
        __syncthreads();
    }

    // ---- epilogue ----
    #pragma unroll
    for (int i = 0; i < 4; ++i) {
        int r = row0 + (tm << 2) + i;
        #pragma unroll
        for (int j = 0; j < 4; ++j) {
            int c = col0 + (tn << 2) + j;
            float v = acc[i][j] + bias[c];
            if (dogelu) v = 0.5f * v * (1.0f + erff(v * 0.70710678118654752f));
            if (R1) v += R1[(size_t)r * Mo + c];
            if (R2) v += R2[(size_t)r * Mo + c];
            C[(size_t)r * Mo + c] = v;
        }
    }
}

// ---------------- masked attention core ----------------
// One block of 256 threads per (b, h, q) row.
// scores s_k = (q . k_k) * scale * M[b,q,k]; softmax over k; A = softmax*M;
// A /= (sum(A) + 1e-8); out = A @ V.
// Folded: with e_k = exp(s_k - max), Z = sum e_k, p_k = e_k * M_k:
//   out_d = (sum_k p_k V[k,d]) / (sum_k p_k + 1e-8 * Z)
__global__ __launch_bounds__(256) void attn_kernel(
    const float* __restrict__ Q, const float* __restrict__ K,
    const float* __restrict__ V, const float* __restrict__ M,
    float* __restrict__ O)
{
    __shared__ float qs[HDIM];
    __shared__ float sc[S_LEN];
    __shared__ float mr[S_LEN];
    __shared__ float red[8];
    __shared__ float acc4[4][HDIM];

    const int bid = blockIdx.x;
    const int q = bid & (S_LEN - 1);
    const int h = (bid >> 11) & (NHEAD - 1);
    const int b = bid >> 14;
    const int tid = threadIdx.x;
    const float scale = 0.125f;   // 64^-0.5

    const float* qptr = Q + ((size_t)(b * S_LEN + q)) * DMODEL + h * HDIM;
    if (tid < HDIM) qs[tid] = qptr[tid];
    __syncthreads();

    // phase 1: masked scores + local max
    const float* Kbase = K + (size_t)b * S_LEN * DMODEL + h * HDIM;
    const float* Mrow  = M + (size_t)b * S_LEN * S_LEN + (size_t)q * S_LEN;
    float lmax = -INFINITY;
    for (int k = tid; k < S_LEN; k += 256) {
        const float4* kp = (const float4*)(Kbase + (size_t)k * DMODEL);
        float dot = 0.0f;
        #pragma unroll
        for (int i = 0; i < 16; ++i) {
            float4 kv = kp[i];
            dot += kv.x * qs[4*i] + kv.y * qs[4*i+1] + kv.z * qs[4*i+2] + kv.w * qs[4*i+3];
        }
        float mk = Mrow[k];
        float s = dot * scale * mk;
        sc[k] = s;
        mr[k] = mk;
        lmax = fmaxf(lmax, s);
    }
    float mx = blockReduceMax256(lmax, red);

    // phase 2: exponentials, masked weights, partition sums
    float lz = 0.0f, lzm = 0.0f;
    for (int k = tid; k < S_LEN; k += 256) {
        float e = expf(sc[k] - mx);
        float p = e * mr[k];
        sc[k] = p;
        lz  += e;
        lzm += p;
    }
    float z  = blockReduceSum256(lz, red);
    float zm = blockReduceSum256(lzm, red);
    float inv_den = 1.0f / (zm + 1e-8f * z);

    // phase 3: weighted sum over V
    const int d = tid & 63, kg = tid >> 6;
    const float* Vb = V + (size_t)b * S_LEN * DMODEL + h * HDIM + d;
    float pa = 0.0f;
    for (int k = kg; k < S_LEN; k += 4)
        pa = fmaf(sc[k], Vb[(size_t)k * DMODEL], pa);
    acc4[kg][d] = pa;
    __syncthreads();
    if (tid < HDIM) {
        float o = (acc4[0][tid] + acc4[1][tid] + acc4[2][tid] + acc4[3][tid]) * inv_den;
        O[((size_t)(b * S_LEN + q)) * DMODEL + h * HDIM + tid] = o;
    }
}

// ---------------- launch ----------------
extern "C" void kernel_launch(void* const* d_in, const int* in_sizes, int n_in,
                              void* d_out, int out_size, void* d_ws, size_t ws_size,
                              hipStream_t stream)
{
    const float* gene_emb = (const float*)d_in[0];
    const float* expr_emb = (const float*)d_in[1];
    const float* M        = (const float*)d_in[2];
    const float* g_wq = (const float*)d_in[3];
    const float* g_wk = (const float*)d_in[4];
    const float* g_wv = (const float*)d_in[5];
    const float* g_wo = (const float*)d_in[6];
    const float* g_bq = (const float*)d_in[7];
    const float* g_bk = (const float*)d_in[8];
    const float* g_bv = (const float*)d_in[9];
    const float* g_bo = (const float*)d_in[10];
    const float* e_wf = (const float*)d_in[11];
    const float* e_bf = (const float*)d_in[12];
    const float* e_wq = (const float*)d_in[13];
    const float* e_wk = (const float*)d_in[14];
    const float* e_wv = (const float*)d_in[15];
    const float* e_wo = (const float*)d_in[16];
    const float* e_bq = (const float*)d_in[17];
    const float* e_bk = (const float*)d_in[18];
    const float* e_bv = (const float*)d_in[19];
    const float* e_bo = (const float*)d_in[20];
    const float* ln_g1_w = (const float*)d_in[21];
    const float* ln_g2_w = (const float*)d_in[22];
    const float* ln_e1_w = (const float*)d_in[23];
    const float* ln_e2_w = (const float*)d_in[24];
    const float* ln_g1_b = (const float*)d_in[25];
    const float* ln_g2_b = (const float*)d_in[26];
    const float* ln_e1_b = (const float*)d_in[27];
    const float* ln_e2_b = (const float*)d_in[28];
    const float* fg_w1 = (const float*)d_in[29];
    const float* fg_b1 = (const float*)d_in[30];
    const float* fg_w2 = (const float*)d_in[31];
    const float* fg_b2 = (const float*)d_in[32];
    const float* fe_w1 = (const float*)d_in[33];
    const float* fe_b1 = (const float*)d_in[34];
    const float* fe_w2 = (const float*)d_in[35];
    const float* fe_b2 = (const float*)d_in[36];

    float* out_gene = (float*)d_out;
    float* out_expr = out_gene + (size_t)NROWS * DMODEL;

    // Workspace layout (floats). 8 MB per activation buffer; bufH (32 MB for
    // FFN hidden) aliases Q/K/V/At which are dead during the FFN. Total 56 MB.
    float* ws = (float*)d_ws;
    const size_t MB = (size_t)NROWS * DMODEL;   // 2M floats
    float* bufA  = ws;             // LN out / fused / x_ln / y_ln
    float* bufQ  = ws + 1 * MB;
    float* bufK  = ws + 2 * MB;
    float* bufV  = ws + 3 * MB;
    float* bufAt = ws + 4 * MB;    // attention core output
    float* bufX  = ws + 5 * MB;    // residual stream x / y
    float* bufYn = ws + 6 * MB;    // y_n (expr LN1)
    float* bufH  = ws + 1 * MB;    // FFN hidden, aliases Q..At (32 MB)

    dim3 blk(256);
    dim3 ln_grid(NROWS);
    dim3 g512(DMODEL / 64, NROWS / 64);   // (8, 64)
    dim3 g2048(2048 / 64, NROWS / 64);    // (32, 64)
    dim3 attn_grid(2 * NHEAD * S_LEN);    // 32768

    // ---------------- gene branch ----------------
    ln_kernel<<<ln_grid, blk, 0, stream>>>(gene_emb, ln_g1_w, ln_g1_b, bufA);
    gemm_kernel<<<g512, blk, 0, stream>>>(bufA, nullptr, 512, g_wq, g_bq, nullptr, nullptr, bufQ, 512, 512, 0);
    gemm_kernel<<<g512, blk, 0, stream>>>(bufA, nullptr, 512, g_wk, g_bk, nullptr, nullptr, bufK, 512, 512, 0);
    gemm_kernel<<<g512, blk, 0, stream>>>(bufA, nullptr, 512, g_wv, g_bv, nullptr, nullptr, bufV, 512, 512, 0);
    attn_kernel<<<attn_grid, blk, 0, stream>>>(bufQ, bufK, bufV, M, bufAt);
    // x = gene_emb + attn @ wo + bo
    gemm_kernel<<<g512, blk, 0, stream>>>(bufAt, nullptr, 512, g_wo, g_bo, gene_emb, nullptr, bufX, 512, 512, 0);
    ln_kernel<<<ln_grid, blk, 0, stream>>>(bufX, ln_g2_w, ln_g2_b, bufA);
    // h = gelu(x_ln @ w1 + b1)
    gemm_kernel<<<g2048, blk, 0, stream>>>(bufA, nullptr, 512, fg_w1, fg_b1, nullptr, nullptr, bufH, 512, 2048, 1);
    // out_gene = x + x_ln + h @ w2 + b2
    gemm_kernel<<<g512, blk, 0, stream>>>(bufH, nullptr, 2048, fg_w2, fg_b2, bufX, bufA, out_gene, 2048, 512, 0);

    // ---------------- expr branch ----------------
    ln_kernel<<<ln_grid, blk, 0, stream>>>(expr_emb, ln_e1_w, ln_e1_b, bufYn);
    // fused = [gene_emb | y_n] @ e_wf + e_bf
    gemm_kernel<<<g512, blk, 0, stream>>>(gene_emb, bufYn, 512, e_wf, e_bf, nullptr, nullptr, bufA, 1024, 512, 0);
    gemm_kernel<<<g512, blk, 0, stream>>>(bufA, nullptr, 512, e_wq, e_bq, nullptr, nullptr, bufQ, 512, 512, 0);
    gemm_kernel<<<g512, blk, 0, stream>>>(bufA, nullptr, 512, e_wk, e_bk, nullptr, nullptr, bufK, 512, 512, 0);
    gemm_kernel<<<g512, blk, 0, stream>>>(bufYn, nullptr, 512, e_wv, e_bv, nullptr, nullptr, bufV, 512, 512, 0);
    attn_kernel<<<attn_grid, blk, 0, stream>>>(bufQ, bufK, bufV, M, bufAt);
    // y = expr_emb + attn @ wo + bo
    gemm_kernel<<<g512, blk, 0, stream>>>(bufAt, nullptr, 512, e_wo, e_bo, expr_emb, nullptr, bufX, 512, 512, 0);
    ln_kernel<<<ln_grid, blk, 0, stream>>>(bufX, ln_e2_w, ln_e2_b, bufA);
    gemm_kernel<<<g2048, blk, 0, stream>>>(bufA, nullptr, 512, fe_w1, fe_b1, nullptr, nullptr, bufH, 512, 2048, 1);
    gemm_kernel<<<g512, blk, 0, stream>>>(bufH, nullptr, 2048, fe_w2, fe_b2, bufX, bufA, out_expr, 2048, 512, 0);
}

// Round 2
// 1762.192 us; speedup vs baseline: 4.7210x; 4.7210x over previous
//
#include <hip/hip_runtime.h>
#include <math.h>

// Problem constants
#define S_LEN 2048
#define DMODEL 512
#define NROWS 4096   // B*S
#define NHEAD 8
#define HDIM 64
#define PAD 68

// ---------------- LayerNorm: one block per row of 512 ----------------
__global__ __launch_bounds__(256) void ln_kernel(
    const float* __restrict__ x, const float* __restrict__ w,
    const float* __restrict__ b, float* __restrict__ y)
{
    __shared__ float red[8];
    const int row = blockIdx.x;
    const float* xr = x + (size_t)row * DMODEL;
    const int t = threadIdx.x;
    float v0 = xr[t];
    float v1 = xr[t + 256];
    float s  = v0 + v1;
    float sq = v0 * v0 + v1 * v1;
    #pragma unroll
    for (int o = 32; o > 0; o >>= 1) {
        s  += __shfl_down(s, o);
        sq += __shfl_down(sq, o);
    }
    int wid = t >> 6, lane = t & 63;
    if (lane == 0) { red[wid] = s; red[4 + wid] = sq; }
    __syncthreads();
    float mean = (red[0] + red[1] + red[2] + red[3]) * (1.0f / 512.0f);
    float msq  = (red[4] + red[5] + red[6] + red[7]) * (1.0f / 512.0f);
    float var  = msq - mean * mean;
    float rs   = rsqrtf(var + 1e-5f);
    y[(size_t)row * DMODEL + t]       = (v0 - mean) * rs * w[t] + b[t];
    y[(size_t)row * DMODEL + t + 256] = (v1 - mean) * rs * w[t + 256] + b[t + 256];
}

// ---------------- generic tiled fp32 GEMM ----------------
__global__ __launch_bounds__(256) void gemm_kernel(
    const float* __restrict__ A1, const float* __restrict__ A2, int lda,
    const float* __restrict__ W, const float* __restrict__ bias,
    const float* __restrict__ R1, const float* __restrict__ R2,
    float* __restrict__ C, int K, int Mo, int dogelu)
{
    __shared__ __align__(16) float As[16][68];  // [k][m], padded rows
    __shared__ __align__(16) float Bs[16][64];  // [k][n]
    const int tid  = threadIdx.x;
    const int row0 = blockIdx.y * 64;
    const int col0 = blockIdx.x * 64;
    const int tn = tid & 15, tm = tid >> 4;

    float acc[4][4];
    #pragma unroll
    for (int i = 0; i < 4; ++i)
        #pragma unroll
        for (int j = 0; j < 4; ++j) acc[i][j] = 0.0f;

    const int lm = tid >> 2;          // 0..63  (A tile row)
    const int lk = (tid & 3) << 2;    // 0,4,8,12 (A tile k)
    const int bk = tid >> 4;          // 0..15  (B tile k)
    const int bn = (tid & 15) << 2;   // B tile col*4

    for (int k0 = 0; k0 < K; k0 += 16) {
        int kg = k0 + lk;
        const float* src = A1; int col = kg;
        if (A2 != nullptr && kg >= 512) { src = A2; col = kg - 512; }
        float4 av = *(const float4*)(src + (size_t)(row0 + lm) * lda + col);
        As[lk + 0][lm] = av.x;
        As[lk + 1][lm] = av.y;
        As[lk + 2][lm] = av.z;
        As[lk + 3][lm] = av.w;
        float4 bv = *(const float4*)(W + (size_t)(k0 + bk) * Mo + col0 + bn);
        *(float4*)&Bs[bk][bn] = bv;
        __syncthreads();
        #pragma unroll
        for (int kk = 0; kk < 16; ++kk) {
            float4 a = *(const float4*)&As[kk][tm << 2];
            float4 b = *(const float4*)&Bs[kk][tn << 2];
            float ar[4] = {a.x, a.y, a.z, a.w};
            float br[4] = {b.x, b.y, b.z, b.w};
            #pragma unroll
            for (int i = 0; i < 4; ++i)
                #pragma unroll
                for (int j = 0; j < 4; ++j)
                    acc[i][j] = fmaf(ar[i], br[j], acc[i][j]);
        }
        __syncthreads();
    }

    #pragma unroll
    for (int i = 0; i < 4; ++i) {
        int r = row0 + (tm << 2) + i;
        #pragma unroll
        for (int j = 0; j < 4; ++j) {
            int c = col0 + (tn << 2) + j;
            float v = acc[i][j] + bias[c];
            if (dogelu) v = 0.5f * v * (1.0f + erff(v * 0.70710678118654752f));
            if (R1) v += R1[(size_t)r * Mo + c];
            if (R2) v += R2[(size_t)r * Mo + c];
            C[(size_t)r * Mo + c] = v;
        }
    }
}

// ---------------- tiled flash-style masked attention ----------------
// One block per (b, h, 64-row q-tile). Online softmax with running
// (m, Z=sum e, Zm=sum e*M) per row; out = (sum e*M*V) / (Zm + 1e-8*Z).
__global__ __launch_bounds__(256) void attn_tile_kernel(
    const float* __restrict__ Q, const float* __restrict__ K,
    const float* __restrict__ V, const float* __restrict__ M,
    float* __restrict__ O)
{
    __shared__ __align__(16) float Qs[64][PAD];  // [d][i]
    __shared__ __align__(16) float Ks[64][PAD];  // [d][j]
    __shared__ __align__(16) float Vs[64][PAD];  // [j][d]
    __shared__ __align__(16) float Ps[64][PAD];  // [j][i]
    __shared__ float rowm[64], rowZ[64], rowZm[64], alpha_s[64];

    const int bh = blockIdx.y;          // 0..15
    const int b = bh >> 3, h = bh & 7;
    const int q0 = blockIdx.x * 64;
    const int tid = threadIdx.x;
    const int tn = tid & 15, tm = tid >> 4;
    const int iB = tm << 2, jB = tn << 2;   // row block, col/d block
    const float scale = 0.125f;             // 64^-0.5

    // ---- load Q tile transposed: Qs[d][i] = Q[b, q0+i, h*64+d] ----
    {
        int i = tid >> 2;
        const float* qrow = Q + ((size_t)(b * S_LEN + q0 + i)) * DMODEL + h * HDIM;
        #pragma unroll
        for (int p = 0; p < 4; ++p) {
            int d = ((tid & 3) << 4) + (p << 2);
            float4 v = *(const float4*)(qrow + d);
            Qs[d + 0][i] = v.x; Qs[d + 1][i] = v.y;
            Qs[d + 2][i] = v.z; Qs[d + 3][i] = v.w;
        }
    }
    if (tid < 64) { rowm[tid] = -INFINITY; rowZ[tid] = 0.0f; rowZm[tid] = 0.0f; }

    float Oacc[4][4] = {{0.f}};

    const float* Kb = K + (size_t)b * S_LEN * DMODEL + h * HDIM;
    const float* Vb = V + (size_t)b * S_LEN * DMODEL + h * HDIM;
    const float* Mb = M + (size_t)b * S_LEN * S_LEN;

    for (int k0 = 0; k0 < S_LEN; k0 += 64) {
        __syncthreads();   // protect Ks/Vs/Ps from previous iteration's readers
        // ---- stage K (transposed) and V (direct) ----
        {
            int j = tid >> 2;
            const float* krow = Kb + (size_t)(k0 + j) * DMODEL;
            const float* vrow = Vb + (size_t)(k0 + j) * DMODEL;
            #pragma unroll
            for (int p = 0; p < 4; ++p) {
                int d = ((tid & 3) << 4) + (p << 2);
                float4 kv = *(const float4*)(krow + d);
                Ks[d + 0][j] = kv.x; Ks[d + 1][j] = kv.y;
                Ks[d + 2][j] = kv.z; Ks[d + 3][j] = kv.w;
                *(float4*)&Vs[j][d] = *(const float4*)(vrow + d);
            }
        }
        __syncthreads();

        // ---- S tile: s[ii][jj] for rows iB+ii, cols jB+jj ----
        float s[4][4] = {{0.f}};
        #pragma unroll 4
        for (int d = 0; d < 64; ++d) {
            float4 a = *(const float4*)&Qs[d][iB];
            float4 kq = *(const float4*)&Ks[d][jB];
            float ar[4] = {a.x, a.y, a.z, a.w};
            float br[4] = {kq.x, kq.y, kq.z, kq.w};
            #pragma unroll
            for (int ii = 0; ii < 4; ++ii)
                #pragma unroll
                for (int jj = 0; jj < 4; ++jj)
                    s[ii][jj] = fmaf(ar[ii], br[jj], s[ii][jj]);
        }

        // ---- scale + mask; per-row tile max ----
        float mk[4][4];
        float tmax[4];
        #pragma unroll
        for (int ii = 0; ii < 4; ++ii) {
            float4 m4 = *(const float4*)(Mb + (size_t)(q0 + iB + ii) * S_LEN + k0 + jB);
            mk[ii][0] = m4.x; mk[ii][1] = m4.y; mk[ii][2] = m4.z; mk[ii][3] = m4.w;
            #pragma unroll
            for (int jj = 0; jj < 4; ++jj)
                s[ii][jj] = s[ii][jj] * scale * mk[ii][jj];
            tmax[ii] = fmaxf(fmaxf(s[ii][0], s[ii][1]), fmaxf(s[ii][2], s[ii][3]));
        }
        #pragma unroll
        for (int o = 1; o < 16; o <<= 1)
            #pragma unroll
            for (int ii = 0; ii < 4; ++ii)
                tmax[ii] = fmaxf(tmax[ii], __shfl_xor(tmax[ii], o));

        // ---- row-state update (one owner thread per row) ----
        if (tn == 0) {
            #pragma unroll
            for (int ii = 0; ii < 4; ++ii) {
                int i = iB + ii;
                float mo = rowm[i];
                float mn = fmaxf(mo, tmax[ii]);
                float al = __expf(mo - mn);    // -inf -> 0 on first tile
                rowm[i] = mn; alpha_s[i] = al;
                rowZ[i] *= al; rowZm[i] *= al;
            }
        }
        __syncthreads();

        // ---- exponentials, masked weights, partial sums, write P ----
        float zp[4], zmp[4];
        #pragma unroll
        for (int ii = 0; ii < 4; ++ii) {
            float mn = rowm[iB + ii];
            zp[ii] = 0.f; zmp[ii] = 0.f;
            #pragma unroll
            for (int jj = 0; jj < 4; ++jj) {
                float e = __expf(s[ii][jj] - mn);
                float p = e * mk[ii][jj];
                zp[ii] += e; zmp[ii] += p;
                Ps[jB + jj][iB + ii] = p;
            }
        }
        #pragma unroll
        for (int o = 1; o < 16; o <<= 1)
            #pragma unroll
            for (int ii = 0; ii < 4; ++ii) {
                zp[ii]  += __shfl_xor(zp[ii], o);
                zmp[ii] += __shfl_xor(zmp[ii], o);
            }
        if (tn == 0) {
            #pragma unroll
            for (int ii = 0; ii < 4; ++ii) {
                rowZ[iB + ii]  += zp[ii];
                rowZm[iB + ii] += zmp[ii];
            }
        }
        // ---- rescale O accumulator ----
        #pragma unroll
        for (int ii = 0; ii < 4; ++ii) {
            float al = alpha_s[iB + ii];
            #pragma unroll
            for (int dd = 0; dd < 4; ++dd) Oacc[ii][dd] *= al;
        }
        __syncthreads();   // Ps fully written

        // ---- O += P @ V ----
        #pragma unroll 4
        for (int j = 0; j < 64; ++j) {
            float4 p4 = *(const float4*)&Ps[j][iB];
            float4 v4 = *(const float4*)&Vs[j][jB];
            float pr[4] = {p4.x, p4.y, p4.z, p4.w};
            float vr[4] = {v4.x, v4.y, v4.z, v4.w};
            #pragma unroll
            for (int ii = 0; ii < 4; ++ii)
                #pragma unroll
                for (int dd = 0; dd < 4; ++dd)
                    Oacc[ii][dd] = fmaf(pr[ii], vr[dd], Oacc[ii][dd]);
        }
    }

    // ---- epilogue: divide and store ----
    #pragma unroll
    for (int ii = 0; ii < 4; ++ii) {
        int i = iB + ii;
        float inv = 1.0f / (rowZm[i] + 1e-8f * rowZ[i]);
        float4 o4;
        o4.x = Oacc[ii][0] * inv; o4.y = Oacc[ii][1] * inv;
        o4.z = Oacc[ii][2] * inv; o4.w = Oacc[ii][3] * inv;
        *(float4*)(O + ((size_t)(b * S_LEN + q0 + i)) * DMODEL + h * HDIM + jB) = o4;
    }
}

// ---------------- launch ----------------
extern "C" void kernel_launch(void* const* d_in, const int* in_sizes, int n_in,
                              void* d_out, int out_size, void* d_ws, size_t ws_size,
                              hipStream_t stream)
{
    const float* gene_emb = (const float*)d_in[0];
    const float* expr_emb = (const float*)d_in[1];
    const float* M        = (const float*)d_in[2];
    const float* g_wq = (const float*)d_in[3];
    const float* g_wk = (const float*)d_in[4];
    const float* g_wv = (const float*)d_in[5];
    const float* g_wo = (const float*)d_in[6];
    const float* g_bq = (const float*)d_in[7];
    const float* g_bk = (const float*)d_in[8];
    const float* g_bv = (const float*)d_in[9];
    const float* g_bo = (const float*)d_in[10];
    const float* e_wf = (const float*)d_in[11];
    const float* e_bf = (const float*)d_in[12];
    const float* e_wq = (const float*)d_in[13];
    const float* e_wk = (const float*)d_in[14];
    const float* e_wv = (const float*)d_in[15];
    const float* e_wo = (const float*)d_in[16];
    const float* e_bq = (const float*)d_in[17];
    const float* e_bk = (const float*)d_in[18];
    const float* e_bv = (const float*)d_in[19];
    const float* e_bo = (const float*)d_in[20];
    const float* ln_g1_w = (const float*)d_in[21];
    const float* ln_g2_w = (const float*)d_in[22];
    const float* ln_e1_w = (const float*)d_in[23];
    const float* ln_e2_w = (const float*)d_in[24];
    const float* ln_g1_b = (const float*)d_in[25];
    const float* ln_g2_b = (const float*)d_in[26];
    const float* ln_e1_b = (const float*)d_in[27];
    const float* ln_e2_b = (const float*)d_in[28];
    const float* fg_w1 = (const float*)d_in[29];
    const float* fg_b1 = (const float*)d_in[30];
    const float* fg_w2 = (const float*)d_in[31];
    const float* fg_b2 = (const float*)d_in[32];
    const float* fe_w1 = (const float*)d_in[33];
    const float* fe_b1 = (const float*)d_in[34];
    const float* fe_w2 = (const float*)d_in[35];
    const float* fe_b2 = (const float*)d_in[36];

    float* out_gene = (float*)d_out;
    float* out_expr = out_gene + (size_t)NROWS * DMODEL;

    float* ws = (float*)d_ws;
    const size_t MB = (size_t)NROWS * DMODEL;   // 2M floats
    float* bufA  = ws;             // LN out / fused / x_ln / y_ln
    float* bufQ  = ws + 1 * MB;
    float* bufK  = ws + 2 * MB;
    float* bufV  = ws + 3 * MB;
    float* bufAt = ws + 4 * MB;    // attention core output
    float* bufX  = ws + 5 * MB;    // residual stream x / y
    float* bufYn = ws + 6 * MB;    // y_n (expr LN1)
    float* bufH  = ws + 1 * MB;    // FFN hidden, aliases Q..At (32 MB)

    dim3 blk(256);
    dim3 ln_grid(NROWS);
    dim3 g512(DMODEL / 64, NROWS / 64);   // (8, 64)
    dim3 g2048(2048 / 64, NROWS / 64);    // (32, 64)
    dim3 attn_grid(S_LEN / 64, 16);       // (32, b*h)

    // ---------------- gene branch ----------------
    ln_kernel<<<ln_grid, blk, 0, stream>>>(gene_emb, ln_g1_w, ln_g1_b, bufA);
    gemm_kernel<<<g512, blk, 0, stream>>>(bufA, nullptr, 512, g_wq, g_bq, nullptr, nullptr, bufQ, 512, 512, 0);
    gemm_kernel<<<g512, blk, 0, stream>>>(bufA, nullptr, 512, g_wk, g_bk, nullptr, nullptr, bufK, 512, 512, 0);
    gemm_kernel<<<g512, blk, 0, stream>>>(bufA, nullptr, 512, g_wv, g_bv, nullptr, nullptr, bufV, 512, 512, 0);
    attn_tile_kernel<<<attn_grid, blk, 0, stream>>>(bufQ, bufK, bufV, M, bufAt);
    gemm_kernel<<<g512, blk, 0, stream>>>(bufAt, nullptr, 512, g_wo, g_bo, gene_emb, nullptr, bufX, 512, 512, 0);
    ln_kernel<<<ln_grid, blk, 0, stream>>>(bufX, ln_g2_w, ln_g2_b, bufA);
    gemm_kernel<<<g2048, blk, 0, stream>>>(bufA, nullptr, 512, fg_w1, fg_b1, nullptr, nullptr, bufH, 512, 2048, 1);
    gemm_kernel<<<g512, blk, 0, stream>>>(bufH, nullptr, 2048, fg_w2, fg_b2, bufX, bufA, out_gene, 2048, 512, 0);

    // ---------------- expr branch ----------------
    ln_kernel<<<ln_grid, blk, 0, stream>>>(expr_emb, ln_e1_w, ln_e1_b, bufYn);
    gemm_kernel<<<g512, blk, 0, stream>>>(gene_emb, bufYn, 512, e_wf, e_bf, nullptr, nullptr, bufA, 1024, 512, 0);
    gemm_kernel<<<g512, blk, 0, stream>>>(bufA, nullptr, 512, e_wq, e_bq, nullptr, nullptr, bufQ, 512, 512, 0);
    gemm_kernel<<<g512, blk, 0, stream>>>(bufA, nullptr, 512, e_wk, e_bk, nullptr, nullptr, bufK, 512, 512, 0);
    gemm_kernel<<<g512, blk, 0, stream>>>(bufYn, nullptr, 512, e_wv, e_bv, nullptr, nullptr, bufV, 512, 512, 0);
    attn_tile_kernel<<<attn_grid, blk, 0, stream>>>(bufQ, bufK, bufV, M, bufAt);
    gemm_kernel<<<g512, blk, 0, stream>>>(bufAt, nullptr, 512, e_wo, e_bo, expr_emb, nullptr, bufX, 512, 512, 0);
    ln_kernel<<<ln_grid, blk, 0, stream>>>(bufX, ln_e2_w, ln_e2_b, bufA);
    gemm_kernel<<<g2048, blk, 0, stream>>>(bufA, nullptr, 512, fe_w1, fe_b1, nullptr, nullptr, bufH, 512, 2048, 1);
    gemm_kernel<<<g512, blk, 0, stream>>>(bufH, nullptr, 2048, fe_w2, fe_b2, bufX, bufA, out_expr, 2048, 512, 0);
}

// Round 3
// 1211.159 us; speedup vs baseline: 6.8688x; 1.4550x over previous
//
#include <hip/hip_runtime.h>
#include <math.h>

// Problem constants
#define S_LEN 2048
#define DMODEL 512
#define NROWS 4096   // B*S
#define NHEAD 8
#define HDIM 64
#define PAD 68

typedef __attribute__((ext_vector_type(8))) __bf16 bf16x8;
typedef __attribute__((ext_vector_type(4))) float f32x4;

__device__ inline float bf2f(unsigned short h) {
    unsigned u = ((unsigned)h) << 16;
    return __builtin_bit_cast(float, u);
}
__device__ inline unsigned short f2bf(float f) {
    unsigned u = __builtin_bit_cast(unsigned, f);
    return (unsigned short)((u + 0x7fffu + ((u >> 16) & 1u)) >> 16);
}

// ---------------- weight cast + transpose: Wt[mo][k] = bf16(W[k][mo]) ------
__global__ __launch_bounds__(256) void wcast_t(
    const float* __restrict__ W, unsigned short* __restrict__ Wt, int K, int Mo)
{
    __shared__ float t[32][33];
    const int bx = blockIdx.x * 32;   // Mo
    const int by = blockIdx.y * 32;   // K
    const int tx = threadIdx.x & 31, ty = threadIdx.x >> 5;  // ty 0..7
    #pragma unroll
    for (int r = 0; r < 4; ++r)
        t[ty + 8 * r][tx] = W[(size_t)(by + ty + 8 * r) * Mo + bx + tx];
    __syncthreads();
    #pragma unroll
    for (int r = 0; r < 4; ++r)
        Wt[(size_t)(bx + ty + 8 * r) * K + by + tx] = f2bf(t[tx][ty + 8 * r]);
}

// ---------------- strided fp32 -> bf16 cast (gene_emb -> concat left) ------
__global__ __launch_bounds__(256) void cast_strided(
    const float* __restrict__ in, unsigned short* __restrict__ out, int ostride)
{
    const int row = blockIdx.x, t = threadIdx.x;
    out[(size_t)row * ostride + t]       = f2bf(in[(size_t)row * DMODEL + t]);
    out[(size_t)row * ostride + t + 256] = f2bf(in[(size_t)row * DMODEL + t + 256]);
}

// ---------------- LayerNorm: fp32 in, bf16 out (strided) ----------------
__global__ __launch_bounds__(256) void ln_kernel(
    const float* __restrict__ x, const float* __restrict__ w,
    const float* __restrict__ b, unsigned short* __restrict__ y, int ostride)
{
    __shared__ float red[8];
    const int row = blockIdx.x;
    const float* xr = x + (size_t)row * DMODEL;
    const int t = threadIdx.x;
    float v0 = xr[t];
    float v1 = xr[t + 256];
    float s  = v0 + v1;
    float sq = v0 * v0 + v1 * v1;
    #pragma unroll
    for (int o = 32; o > 0; o >>= 1) {
        s  += __shfl_down(s, o);
        sq += __shfl_down(sq, o);
    }
    int wid = t >> 6, lane = t & 63;
    if (lane == 0) { red[wid] = s; red[4 + wid] = sq; }
    __syncthreads();
    float mean = (red[0] + red[1] + red[2] + red[3]) * (1.0f / 512.0f);
    float msq  = (red[4] + red[5] + red[6] + red[7]) * (1.0f / 512.0f);
    float var  = msq - mean * mean;
    float rs   = rsqrtf(var + 1e-5f);
    y[(size_t)row * ostride + t]       = f2bf((v0 - mean) * rs * w[t] + b[t]);
    y[(size_t)row * ostride + t + 256] = f2bf((v1 - mean) * rs * w[t + 256] + b[t + 256]);
}

// ---------------- bf16 MFMA GEMM, 128x128 tile, BK=32 ----------------
// C[4096][Mo] = epi( A[4096][lda(bf16)] @ W ), B = Wt[Mo][K] bf16 row-major.
// Epilogue: +bias, optional exact GELU, +R1 (fp32), +R2 (bf16), out fp32 or bf16.
__global__ __launch_bounds__(256) void gemm_mfma(
    const unsigned short* __restrict__ A, int lda,
    const unsigned short* __restrict__ Bt,
    const float* __restrict__ bias,
    const float* __restrict__ R1,
    const unsigned short* __restrict__ R2,
    float* __restrict__ Cf, unsigned short* __restrict__ Cb,
    int K, int Mo, int dogelu)
{
    __shared__ __align__(16) unsigned short As[128 * 32];
    __shared__ __align__(16) unsigned short Bs[128 * 32];
    const int tid = threadIdx.x;
    const int wave = tid >> 6, lane = tid & 63;
    const int wr = wave >> 1, wc = wave & 1;
    const int row0 = blockIdx.y * 128, col0 = blockIdx.x * 128;
    const int l15 = lane & 15, q = lane >> 4;

    f32x4 acc[4][4];
    const f32x4 zz = {0.f, 0.f, 0.f, 0.f};
    #pragma unroll
    for (int i = 0; i < 4; ++i)
        #pragma unroll
        for (int j = 0; j < 4; ++j) acc[i][j] = zz;

    for (int k0 = 0; k0 < K; k0 += 32) {
        // ---- stage 128x32 bf16 A and B tiles (16B per thread per round) ----
        #pragma unroll
        for (int r = 0; r < 2; ++r) {
            int idx = r * 256 + tid;
            int row = idx >> 2, kc = idx & 3;
            *(int4*)&As[row * 32 + kc * 8] =
                *(const int4*)&A[(size_t)(row0 + row) * lda + k0 + kc * 8];
            *(int4*)&Bs[row * 32 + kc * 8] =
                *(const int4*)&Bt[(size_t)(col0 + row) * K + k0 + kc * 8];
        }
        __syncthreads();
        bf16x8 af[4], bfr[4];
        #pragma unroll
        for (int fi = 0; fi < 4; ++fi)
            af[fi] = *(const bf16x8*)&As[(wr * 64 + fi * 16 + l15) * 32 + q * 8];
        #pragma unroll
        for (int fj = 0; fj < 4; ++fj)
            bfr[fj] = *(const bf16x8*)&Bs[(wc * 64 + fj * 16 + l15) * 32 + q * 8];
        #pragma unroll
        for (int fi = 0; fi < 4; ++fi)
            #pragma unroll
            for (int fj = 0; fj < 4; ++fj)
                acc[fi][fj] = __builtin_amdgcn_mfma_f32_16x16x32_bf16(
                    af[fi], bfr[fj], acc[fi][fj], 0, 0, 0);
        __syncthreads();
    }

    // ---- epilogue: C/D layout col=lane&15, row=(lane>>4)*4+reg ----
    #pragma unroll
    for (int fi = 0; fi < 4; ++fi) {
        #pragma unroll
        for (int reg = 0; reg < 4; ++reg) {
            int row = row0 + wr * 64 + fi * 16 + q * 4 + reg;
            #pragma unroll
            for (int fj = 0; fj < 4; ++fj) {
                int col = col0 + wc * 64 + fj * 16 + l15;
                float v = acc[fi][fj][reg] + bias[col];
                if (dogelu) v = 0.5f * v * (1.0f + erff(v * 0.70710678118654752f));
                size_t off = (size_t)row * Mo + col;
                if (R1) v += R1[off];
                if (R2) v += bf2f(R2[off]);
                if (Cb) Cb[off] = f2bf(v);
                else    Cf[off] = v;
            }
        }
    }
}

// ---------------- tiled flash-style masked attention (bf16 QKV in/out) -----
__global__ __launch_bounds__(256) void attn_tile_kernel(
    const unsigned short* __restrict__ Q, const unsigned short* __restrict__ K,
    const unsigned short* __restrict__ V, const float* __restrict__ M,
    unsigned short* __restrict__ O)
{
    __shared__ __align__(16) float Qs[64][PAD];  // [d][i]
    __shared__ __align__(16) float Ks[64][PAD];  // [d][j]
    __shared__ __align__(16) float Vs[64][PAD];  // [j][d]
    __shared__ __align__(16) float Ps[64][PAD];  // [j][i]
    __shared__ float rowm[64], rowZ[64], rowZm[64], alpha_s[64];

    const int bh = blockIdx.y;
    const int b = bh >> 3, h = bh & 7;
    const int q0 = blockIdx.x * 64;
    const int tid = threadIdx.x;
    const int tn = tid & 15, tm = tid >> 4;
    const int iB = tm << 2, jB = tn << 2;
    const float scale = 0.125f;

    // ---- load Q tile transposed: Qs[d][i] = Q[b, q0+i, h*64+d] ----
    {
        int i = tid >> 2;
        const unsigned short* qrow = Q + ((size_t)(b * S_LEN + q0 + i)) * DMODEL + h * HDIM;
        #pragma unroll
        for (int p = 0; p < 2; ++p) {
            int d = ((tid & 3) << 4) + (p << 3);
            union { int4 v; unsigned short u[8]; } tmp;
            tmp.v = *(const int4*)(qrow + d);
            #pragma unroll
            for (int e = 0; e < 8; ++e) Qs[d + e][i] = bf2f(tmp.u[e]);
        }
    }
    if (tid < 64) { rowm[tid] = -INFINITY; rowZ[tid] = 0.0f; rowZm[tid] = 0.0f; }

    float Oacc[4][4] = {{0.f}};

    const unsigned short* Kb = K + (size_t)b * S_LEN * DMODEL + h * HDIM;
    const unsigned short* Vb = V + (size_t)b * S_LEN * DMODEL + h * HDIM;
    const float* Mb = M + (size_t)b * S_LEN * S_LEN;

    for (int k0 = 0; k0 < S_LEN; k0 += 64) {
        __syncthreads();
        // ---- stage K (transposed) and V ----
        {
            int j = tid >> 2;
            const unsigned short* krow = Kb + (size_t)(k0 + j) * DMODEL;
            const unsigned short* vrow = Vb + (size_t)(k0 + j) * DMODEL;
            #pragma unroll
            for (int p = 0; p < 2; ++p) {
                int d = ((tid & 3) << 4) + (p << 3);
                union { int4 v; unsigned short u[8]; } kk, vv;
                kk.v = *(const int4*)(krow + d);
                vv.v = *(const int4*)(vrow + d);
                #pragma unroll
                for (int e = 0; e < 8; ++e) Ks[d + e][j] = bf2f(kk.u[e]);
                float4 lo = {bf2f(vv.u[0]), bf2f(vv.u[1]), bf2f(vv.u[2]), bf2f(vv.u[3])};
                float4 hi = {bf2f(vv.u[4]), bf2f(vv.u[5]), bf2f(vv.u[6]), bf2f(vv.u[7])};
                *(float4*)&Vs[j][d]     = lo;
                *(float4*)&Vs[j][d + 4] = hi;
            }
        }
        __syncthreads();

        // ---- S tile ----
        float s[4][4] = {{0.f}};
        #pragma unroll 4
        for (int d = 0; d < 64; ++d) {
            float4 a = *(const float4*)&Qs[d][iB];
            float4 kq = *(const float4*)&Ks[d][jB];
            float ar[4] = {a.x, a.y, a.z, a.w};
            float br[4] = {kq.x, kq.y, kq.z, kq.w};
            #pragma unroll
            for (int ii = 0; ii < 4; ++ii)
                #pragma unroll
                for (int jj = 0; jj < 4; ++jj)
                    s[ii][jj] = fmaf(ar[ii], br[jj], s[ii][jj]);
        }

        // ---- scale + mask; per-row tile max ----
        float mk[4][4];
        float tmax[4];
        #pragma unroll
        for (int ii = 0; ii < 4; ++ii) {
            float4 m4 = *(const float4*)(Mb + (size_t)(q0 + iB + ii) * S_LEN + k0 + jB);
            mk[ii][0] = m4.x; mk[ii][1] = m4.y; mk[ii][2] = m4.z; mk[ii][3] = m4.w;
            #pragma unroll
            for (int jj = 0; jj < 4; ++jj)
                s[ii][jj] = s[ii][jj] * scale * mk[ii][jj];
            tmax[ii] = fmaxf(fmaxf(s[ii][0], s[ii][1]), fmaxf(s[ii][2], s[ii][3]));
        }
        #pragma unroll
        for (int o = 1; o < 16; o <<= 1)
            #pragma unroll
            for (int ii = 0; ii < 4; ++ii)
                tmax[ii] = fmaxf(tmax[ii], __shfl_xor(tmax[ii], o));

        if (tn == 0) {
            #pragma unroll
            for (int ii = 0; ii < 4; ++ii) {
                int i = iB + ii;
                float mo = rowm[i];
                float mn = fmaxf(mo, tmax[ii]);
                float al = __expf(mo - mn);
                rowm[i] = mn; alpha_s[i] = al;
                rowZ[i] *= al; rowZm[i] *= al;
            }
        }
        __syncthreads();

        float zp[4], zmp[4];
        #pragma unroll
        for (int ii = 0; ii < 4; ++ii) {
            float mn = rowm[iB + ii];
            zp[ii] = 0.f; zmp[ii] = 0.f;
            #pragma unroll
            for (int jj = 0; jj < 4; ++jj) {
                float e = __expf(s[ii][jj] - mn);
                float p = e * mk[ii][jj];
                zp[ii] += e; zmp[ii] += p;
                Ps[jB + jj][iB + ii] = p;
            }
        }
        #pragma unroll
        for (int o = 1; o < 16; o <<= 1)
            #pragma unroll
            for (int ii = 0; ii < 4; ++ii) {
                zp[ii]  += __shfl_xor(zp[ii], o);
                zmp[ii] += __shfl_xor(zmp[ii], o);
            }
        if (tn == 0) {
            #pragma unroll
            for (int ii = 0; ii < 4; ++ii) {
                rowZ[iB + ii]  += zp[ii];
                rowZm[iB + ii] += zmp[ii];
            }
        }
        #pragma unroll
        for (int ii = 0; ii < 4; ++ii) {
            float al = alpha_s[iB + ii];
            #pragma unroll
            for (int dd = 0; dd < 4; ++dd) Oacc[ii][dd] *= al;
        }
        __syncthreads();

        #pragma unroll 4
        for (int j = 0; j < 64; ++j) {
            float4 p4 = *(const float4*)&Ps[j][iB];
            float4 v4 = *(const float4*)&Vs[j][jB];
            float pr[4] = {p4.x, p4.y, p4.z, p4.w};
            float vr[4] = {v4.x, v4.y, v4.z, v4.w};
            #pragma unroll
            for (int ii = 0; ii < 4; ++ii)
                #pragma unroll
                for (int dd = 0; dd < 4; ++dd)
                    Oacc[ii][dd] = fmaf(pr[ii], vr[dd], Oacc[ii][dd]);
        }
    }

    // ---- epilogue ----
    #pragma unroll
    for (int ii = 0; ii < 4; ++ii) {
        int i = iB + ii;
        float inv = 1.0f / (rowZm[i] + 1e-8f * rowZ[i]);
        ushort4 o4;
        o4.x = f2bf(Oacc[ii][0] * inv); o4.y = f2bf(Oacc[ii][1] * inv);
        o4.z = f2bf(Oacc[ii][2] * inv); o4.w = f2bf(Oacc[ii][3] * inv);
        *(ushort4*)(O + ((size_t)(b * S_LEN + q0 + i)) * DMODEL + h * HDIM + jB) = o4;
    }
}

// ---------------- launch ----------------
extern "C" void kernel_launch(void* const* d_in, const int* in_sizes, int n_in,
                              void* d_out, int out_size, void* d_ws, size_t ws_size,
                              hipStream_t stream)
{
    const float* gene_emb = (const float*)d_in[0];
    const float* expr_emb = (const float*)d_in[1];
    const float* M        = (const float*)d_in[2];
    const float* g_wq = (const float*)d_in[3];
    const float* g_wk = (const float*)d_in[4];
    const float* g_wv = (const float*)d_in[5];
    const float* g_wo = (const float*)d_in[6];
    const float* g_bq = (const float*)d_in[7];
    const float* g_bk = (const float*)d_in[8];
    const float* g_bv = (const float*)d_in[9];
    const float* g_bo = (const float*)d_in[10];
    const float* e_wf = (const float*)d_in[11];
    const float* e_bf = (const float*)d_in[12];
    const float* e_wq = (const float*)d_in[13];
    const float* e_wk = (const float*)d_in[14];
    const float* e_wv = (const float*)d_in[15];
    const float* e_wo = (const float*)d_in[16];
    const float* e_bq = (const float*)d_in[17];
    const float* e_bk = (const float*)d_in[18];
    const float* e_bv = (const float*)d_in[19];
    const float* e_bo = (const float*)d_in[20];
    const float* ln_g1_w = (const float*)d_in[21];
    const float* ln_g2_w = (const float*)d_in[22];
    const float* ln_e1_w = (const float*)d_in[23];
    const float* ln_e2_w = (const float*)d_in[24];
    const float* ln_g1_b = (const float*)d_in[25];
    const float* ln_g2_b = (const float*)d_in[26];
    const float* ln_e1_b = (const float*)d_in[27];
    const float* ln_e2_b = (const float*)d_in[28];
    const float* fg_w1 = (const float*)d_in[29];
    const float* fg_b1 = (const float*)d_in[30];
    const float* fg_w2 = (const float*)d_in[31];
    const float* fg_b2 = (const float*)d_in[32];
    const float* fe_w1 = (const float*)d_in[33];
    const float* fe_b1 = (const float*)d_in[34];
    const float* fe_w2 = (const float*)d_in[35];
    const float* fe_b2 = (const float*)d_in[36];

    float* out_gene = (float*)d_out;
    float* out_expr = out_gene + (size_t)NROWS * DMODEL;

    // ---- workspace layout (bytes), total 49 MB ----
    char* ws = (char*)d_ws;
    const size_t MB1 = 1024 * 1024;
    unsigned short* bufA16  = (unsigned short*)(ws + 0 * MB1);   // 4 MB [4096][512]
    unsigned short* bufCat  = (unsigned short*)(ws + 4 * MB1);   // 8 MB [4096][1024]
    unsigned short* bufQ16  = (unsigned short*)(ws + 12 * MB1);  // 4 MB
    unsigned short* bufK16  = (unsigned short*)(ws + 16 * MB1);  // 4 MB
    unsigned short* bufV16  = (unsigned short*)(ws + 20 * MB1);  // 4 MB
    unsigned short* bufAt16 = (unsigned short*)(ws + 24 * MB1);  // 4 MB
    float*          bufX    = (float*)(ws + 28 * MB1);           // 8 MB
    unsigned short* bufH16  = (unsigned short*)(ws + 12 * MB1);  // 16 MB, aliases Q/K/V/At
    // transposed bf16 weights: 13 MB starting at +36 MB
    char* wp = ws + 36 * MB1;
    unsigned short* gwq_t = (unsigned short*)(wp);               wp += 512 * 512 * 2;
    unsigned short* gwk_t = (unsigned short*)(wp);               wp += 512 * 512 * 2;
    unsigned short* gwv_t = (unsigned short*)(wp);               wp += 512 * 512 * 2;
    unsigned short* gwo_t = (unsigned short*)(wp);               wp += 512 * 512 * 2;
    unsigned short* ewf_t = (unsigned short*)(wp);               wp += 1024 * 512 * 2;
    unsigned short* ewq_t = (unsigned short*)(wp);               wp += 512 * 512 * 2;
    unsigned short* ewk_t = (unsigned short*)(wp);               wp += 512 * 512 * 2;
    unsigned short* ewv_t = (unsigned short*)(wp);               wp += 512 * 512 * 2;
    unsigned short* ewo_t = (unsigned short*)(wp);               wp += 512 * 512 * 2;
    unsigned short* fgw1_t = (unsigned short*)(wp);              wp += 512 * 2048 * 2;
    unsigned short* fgw2_t = (unsigned short*)(wp);              wp += 2048 * 512 * 2;
    unsigned short* few1_t = (unsigned short*)(wp);              wp += 512 * 2048 * 2;
    unsigned short* few2_t = (unsigned short*)(wp);              wp += 2048 * 512 * 2;

    dim3 blk(256);
    dim3 ln_grid(NROWS);
    dim3 g512(4, 32);     // Mo=512 tiles
    dim3 g2048(16, 32);   // Mo=2048 tiles
    dim3 attn_grid(S_LEN / 64, 16);

    // ---- weight prep ----
    wcast_t<<<dim3(16, 16), blk, 0, stream>>>(g_wq, gwq_t, 512, 512);
    wcast_t<<<dim3(16, 16), blk, 0, stream>>>(g_wk, gwk_t, 512, 512);
    wcast_t<<<dim3(16, 16), blk, 0, stream>>>(g_wv, gwv_t, 512, 512);
    wcast_t<<<dim3(16, 16), blk, 0, stream>>>(g_wo, gwo_t, 512, 512);
    wcast_t<<<dim3(16, 32), blk, 0, stream>>>(e_wf, ewf_t, 1024, 512);
    wcast_t<<<dim3(16, 16), blk, 0, stream>>>(e_wq, ewq_t, 512, 512);
    wcast_t<<<dim3(16, 16), blk, 0, stream>>>(e_wk, ewk_t, 512, 512);
    wcast_t<<<dim3(16, 16), blk, 0, stream>>>(e_wv, ewv_t, 512, 512);
    wcast_t<<<dim3(16, 16), blk, 0, stream>>>(e_wo, ewo_t, 512, 512);
    wcast_t<<<dim3(64, 16), blk, 0, stream>>>(fg_w1, fgw1_t, 512, 2048);
    wcast_t<<<dim3(16, 64), blk, 0, stream>>>(fg_w2, fgw2_t, 2048, 512);
    wcast_t<<<dim3(64, 16), blk, 0, stream>>>(fe_w1, few1_t, 512, 2048);
    wcast_t<<<dim3(16, 64), blk, 0, stream>>>(fe_w2, few2_t, 2048, 512);
    cast_strided<<<ln_grid, blk, 0, stream>>>(gene_emb, bufCat, 1024);

    // ---------------- gene branch ----------------
    ln_kernel<<<ln_grid, blk, 0, stream>>>(gene_emb, ln_g1_w, ln_g1_b, bufA16, 512);
    gemm_mfma<<<g512, blk, 0, stream>>>(bufA16, 512, gwq_t, g_bq, nullptr, nullptr, nullptr, bufQ16, 512, 512, 0);
    gemm_mfma<<<g512, blk, 0, stream>>>(bufA16, 512, gwk_t, g_bk, nullptr, nullptr, nullptr, bufK16, 512, 512, 0);
    gemm_mfma<<<g512, blk, 0, stream>>>(bufA16, 512, gwv_t, g_bv, nullptr, nullptr, nullptr, bufV16, 512, 512, 0);
    attn_tile_kernel<<<attn_grid, blk, 0, stream>>>(bufQ16, bufK16, bufV16, M, bufAt16);
    gemm_mfma<<<g512, blk, 0, stream>>>(bufAt16, 512, gwo_t, g_bo, gene_emb, nullptr, bufX, nullptr, 512, 512, 0);
    ln_kernel<<<ln_grid, blk, 0, stream>>>(bufX, ln_g2_w, ln_g2_b, bufA16, 512);
    gemm_mfma<<<g2048, blk, 0, stream>>>(bufA16, 512, fgw1_t, fg_b1, nullptr, nullptr, nullptr, bufH16, 512, 2048, 1);
    gemm_mfma<<<g512, blk, 0, stream>>>(bufH16, 2048, fgw2_t, fg_b2, bufX, bufA16, out_gene, nullptr, 2048, 512, 0);

    // ---------------- expr branch ----------------
    ln_kernel<<<ln_grid, blk, 0, stream>>>(expr_emb, ln_e1_w, ln_e1_b, bufCat + 512, 1024);
    gemm_mfma<<<g512, blk, 0, stream>>>(bufCat, 1024, ewf_t, e_bf, nullptr, nullptr, nullptr, bufA16, 1024, 512, 0);
    gemm_mfma<<<g512, blk, 0, stream>>>(bufA16, 512, ewq_t, e_bq, nullptr, nullptr, nullptr, bufQ16, 512, 512, 0);
    gemm_mfma<<<g512, blk, 0, stream>>>(bufA16, 512, ewk_t, e_bk, nullptr, nullptr, nullptr, bufK16, 512, 512, 0);
    gemm_mfma<<<g512, blk, 0, stream>>>(bufCat + 512, 1024, ewv_t, e_bv, nullptr, nullptr, nullptr, bufV16, 512, 512, 0);
    attn_tile_kernel<<<attn_grid, blk, 0, stream>>>(bufQ16, bufK16, bufV16, M, bufAt16);
    gemm_mfma<<<g512, blk, 0, stream>>>(bufAt16, 512, ewo_t, e_bo, expr_emb, nullptr, bufX, nullptr, 512, 512, 0);
    ln_kernel<<<ln_grid, blk, 0, stream>>>(bufX, ln_e2_w, ln_e2_b, bufA16, 512);
    gemm_mfma<<<g2048, blk, 0, stream>>>(bufA16, 512, few1_t, fe_b1, nullptr, nullptr, nullptr, bufH16, 512, 2048, 1);
    gemm_mfma<<<g512, blk, 0, stream>>>(bufH16, 2048, few2_t, fe_b2, bufX, bufA16, out_expr, nullptr, 2048, 512, 0);
}

// Round 4
// 859.706 us; speedup vs baseline: 9.6769x; 1.4088x over previous
//
#include <hip/hip_runtime.h>
#include <math.h>

// Problem constants
#define S_LEN 2048
#define DMODEL 512
#define NROWS 4096   // B*S
#define NHEAD 8
#define HDIM 64

typedef __attribute__((ext_vector_type(8))) __bf16 bf16x8;
typedef __attribute__((ext_vector_type(4))) float f32x4;

__device__ inline float bf2f(unsigned short h) {
    unsigned u = ((unsigned)h) << 16;
    return __builtin_bit_cast(float, u);
}
__device__ inline unsigned short f2bf(float f) {
    unsigned u = __builtin_bit_cast(unsigned, f);
    return (unsigned short)((u + 0x7fffu + ((u >> 16) & 1u)) >> 16);
}

// ---------------- weight cast + transpose: Wt[mo][k] = bf16(W[k][mo]) ------
__global__ __launch_bounds__(256) void wcast_t(
    const float* __restrict__ W, unsigned short* __restrict__ Wt, int K, int Mo)
{
    __shared__ float t[32][33];
    const int bx = blockIdx.x * 32;   // Mo
    const int by = blockIdx.y * 32;   // K
    const int tx = threadIdx.x & 31, ty = threadIdx.x >> 5;  // ty 0..7
    #pragma unroll
    for (int r = 0; r < 4; ++r)
        t[ty + 8 * r][tx] = W[(size_t)(by + ty + 8 * r) * Mo + bx + tx];
    __syncthreads();
    #pragma unroll
    for (int r = 0; r < 4; ++r)
        Wt[(size_t)(bx + ty + 8 * r) * K + by + tx] = f2bf(t[tx][ty + 8 * r]);
}

// ---------------- pack up to 3 bias vectors (512 each) into one ----------
__global__ __launch_bounds__(256) void pack_bias(
    const float* __restrict__ b1, const float* __restrict__ b2,
    const float* __restrict__ b3, float* __restrict__ dst, int n)
{
    int t = blockIdx.x * 256 + threadIdx.x;
    if (t >= n) return;
    float v = (t < 512) ? b1[t] : (t < 1024) ? b2[t - 512] : b3[t - 1024];
    dst[t] = v;
}

// ---------------- strided fp32 -> bf16 cast (gene_emb -> concat left) ------
__global__ __launch_bounds__(256) void cast_strided(
    const float* __restrict__ in, unsigned short* __restrict__ out, int ostride)
{
    const int row = blockIdx.x, t = threadIdx.x;
    out[(size_t)row * ostride + t]       = f2bf(in[(size_t)row * DMODEL + t]);
    out[(size_t)row * ostride + t + 256] = f2bf(in[(size_t)row * DMODEL + t + 256]);
}

// ---------------- LayerNorm: fp32 in, bf16 out (strided) ----------------
__global__ __launch_bounds__(256) void ln_kernel(
    const float* __restrict__ x, const float* __restrict__ w,
    const float* __restrict__ b, unsigned short* __restrict__ y, int ostride)
{
    __shared__ float red[8];
    const int row = blockIdx.x;
    const float* xr = x + (size_t)row * DMODEL;
    const int t = threadIdx.x;
    float v0 = xr[t];
    float v1 = xr[t + 256];
    float s  = v0 + v1;
    float sq = v0 * v0 + v1 * v1;
    #pragma unroll
    for (int o = 32; o > 0; o >>= 1) {
        s  += __shfl_down(s, o);
        sq += __shfl_down(sq, o);
    }
    int wid = t >> 6, lane = t & 63;
    if (lane == 0) { red[wid] = s; red[4 + wid] = sq; }
    __syncthreads();
    float mean = (red[0] + red[1] + red[2] + red[3]) * (1.0f / 512.0f);
    float msq  = (red[4] + red[5] + red[6] + red[7]) * (1.0f / 512.0f);
    float var  = msq - mean * mean;
    float rs   = rsqrtf(var + 1e-5f);
    y[(size_t)row * ostride + t]       = f2bf((v0 - mean) * rs * w[t] + b[t]);
    y[(size_t)row * ostride + t + 256] = f2bf((v1 - mean) * rs * w[t + 256] + b[t + 256]);
}

// ---------------- V transpose: Vt[(b*8+h)*64 + d][s] = V[b*2048+s][h*64+d] --
__global__ __launch_bounds__(256) void vtrans(
    const unsigned short* __restrict__ V, int ldv, unsigned short* __restrict__ Vt)
{
    __shared__ unsigned short t[64][72];
    const int s0 = blockIdx.x * 64, h = blockIdx.y, b = blockIdx.z;
    const int tid = threadIdx.x;
    {
        const int r = tid >> 2, c = (tid & 3) * 16;
        const unsigned short* src = V + (size_t)(b * S_LEN + s0 + r) * ldv + h * 64 + c;
        *(int4*)&t[r][c]     = *(const int4*)(src);
        *(int4*)&t[r][c + 8] = *(const int4*)(src + 8);
    }
    __syncthreads();
    {
        const int d = tid >> 2, s = (tid & 3) * 16;
        unsigned short* dst = Vt + ((size_t)((b * 8 + h) * 64 + d)) * S_LEN + s0 + s;
        unsigned short tmp[16];
        #pragma unroll
        for (int e = 0; e < 16; ++e) tmp[e] = t[s + e][d];
        *(int4*)dst       = *(int4*)&tmp[0];
        *(int4*)(dst + 8) = *(int4*)&tmp[8];
    }
}

// ---------------- bf16 MFMA GEMM, 128x128 tile, BK=32 ----------------
__global__ __launch_bounds__(256) void gemm_mfma(
    const unsigned short* __restrict__ A, int lda,
    const unsigned short* __restrict__ Bt,
    const float* __restrict__ bias,
    const float* __restrict__ R1,
    const unsigned short* __restrict__ R2,
    float* __restrict__ Cf, unsigned short* __restrict__ Cb,
    int K, int Mo, int dogelu)
{
    __shared__ __align__(16) unsigned short As[128 * 32];
    __shared__ __align__(16) unsigned short Bs[128 * 32];
    const int tid = threadIdx.x;
    const int wave = tid >> 6, lane = tid & 63;
    const int wr = wave >> 1, wc = wave & 1;
    const int row0 = blockIdx.y * 128, col0 = blockIdx.x * 128;
    const int l15 = lane & 15, q = lane >> 4;

    f32x4 acc[4][4];
    const f32x4 zz = {0.f, 0.f, 0.f, 0.f};
    #pragma unroll
    for (int i = 0; i < 4; ++i)
        #pragma unroll
        for (int j = 0; j < 4; ++j) acc[i][j] = zz;

    for (int k0 = 0; k0 < K; k0 += 32) {
        #pragma unroll
        for (int r = 0; r < 2; ++r) {
            int idx = r * 256 + tid;
            int row = idx >> 2, kc = idx & 3;
            *(int4*)&As[row * 32 + kc * 8] =
                *(const int4*)&A[(size_t)(row0 + row) * lda + k0 + kc * 8];
            *(int4*)&Bs[row * 32 + kc * 8] =
                *(const int4*)&Bt[(size_t)(col0 + row) * K + k0 + kc * 8];
        }
        __syncthreads();
        bf16x8 af[4], bfr[4];
        #pragma unroll
        for (int fi = 0; fi < 4; ++fi)
            af[fi] = *(const bf16x8*)&As[(wr * 64 + fi * 16 + l15) * 32 + q * 8];
        #pragma unroll
        for (int fj = 0; fj < 4; ++fj)
            bfr[fj] = *(const bf16x8*)&Bs[(wc * 64 + fj * 16 + l15) * 32 + q * 8];
        #pragma unroll
        for (int fi = 0; fi < 4; ++fi)
            #pragma unroll
            for (int fj = 0; fj < 4; ++fj)
                acc[fi][fj] = __builtin_amdgcn_mfma_f32_16x16x32_bf16(
                    af[fi], bfr[fj], acc[fi][fj], 0, 0, 0);
        __syncthreads();
    }

    #pragma unroll
    for (int fi = 0; fi < 4; ++fi) {
        #pragma unroll
        for (int reg = 0; reg < 4; ++reg) {
            int row = row0 + wr * 64 + fi * 16 + q * 4 + reg;
            #pragma unroll
            for (int fj = 0; fj < 4; ++fj) {
                int col = col0 + wc * 64 + fj * 16 + l15;
                float v = acc[fi][fj][reg] + bias[col];
                if (dogelu) v = 0.5f * v * (1.0f + erff(v * 0.70710678118654752f));
                size_t off = (size_t)row * Mo + col;
                if (R1) v += R1[off];
                if (R2) v += bf2f(R2[off]);
                if (Cb) Cb[off] = f2bf(v);
                else    Cf[off] = v;
            }
        }
    }
}

// ---------------- MFMA flash attention ----------------
// Block (q-tile 64, bh). 4 waves, each owns 16 q-rows (i = q0+wave*16+lane&15).
// S^T = K·Q^T (C/D: row=j, col=i) so softmax state is per-lane registers and
// mask loads are float4. O^T = V^T·P with P round-tripped via per-wave LDS.
// out = sum(e*M*V) / (sum(e*M) + 1e-8*sum(e)).
__global__ __launch_bounds__(256) void attn_mfma(
    const unsigned short* __restrict__ Q, int ldq,
    const unsigned short* __restrict__ Kp, int ldk,
    const unsigned short* __restrict__ Vt,   // [16 bh][64 d][2048 s]
    const float* __restrict__ M,
    unsigned short* __restrict__ O)          // [4096][512]
{
    __shared__ unsigned short Ps[4][16][72];
    const int bh = blockIdx.y, b = bh >> 3, h = bh & 7;
    const int q0 = blockIdx.x * 64;
    const int tid = threadIdx.x, wave = tid >> 6, lane = tid & 63;
    const int l15 = lane & 15, quad = lane >> 4;
    const int iRow = q0 + wave * 16 + l15;

    // Q fragments (B-operand: B[n=i][k=d]), pre-scaled by 1/8 (exact in bf16)
    bf16x8 qf[2];
    {
        const unsigned short* qp = Q + (size_t)(b * S_LEN + iRow) * ldq + h * HDIM + quad * 8;
        #pragma unroll
        for (int ks = 0; ks < 2; ++ks) {
            union { bf16x8 v; unsigned short u[8]; } tq;
            tq.v = *(const bf16x8*)(qp + ks * 32);
            #pragma unroll
            for (int e = 0; e < 8; ++e) tq.u[e] = f2bf(bf2f(tq.u[e]) * 0.125f);
            qf[ks] = tq.v;
        }
    }

    float rm = -INFINITY, rZ = 0.f, rZm = 0.f;
    f32x4 oacc[4];
    const f32x4 zz = {0.f, 0.f, 0.f, 0.f};
    #pragma unroll
    for (int dt = 0; dt < 4; ++dt) oacc[dt] = zz;

    const unsigned short* kbase = Kp + (size_t)(b * S_LEN + l15) * ldk + h * HDIM + quad * 8;
    const unsigned short* vbase = Vt + ((size_t)(bh * 64 + l15)) * S_LEN + quad * 8;
    const float* mbase = M + (size_t)b * S_LEN * S_LEN + (size_t)iRow * S_LEN + quad * 4;

    for (int k0 = 0; k0 < S_LEN; k0 += 64) {
        // ---- fragment loads straight from global ----
        bf16x8 kf[4][2], vf[4][2];
        #pragma unroll
        for (int mt = 0; mt < 4; ++mt)
            #pragma unroll
            for (int ks = 0; ks < 2; ++ks)
                kf[mt][ks] = *(const bf16x8*)(kbase + (size_t)(k0 + mt * 16) * ldk + ks * 32);
        #pragma unroll
        for (int dt = 0; dt < 4; ++dt)
            #pragma unroll
            for (int ks = 0; ks < 2; ++ks)
                vf[dt][ks] = *(const bf16x8*)(vbase + (size_t)(dt * 16) * S_LEN + k0 + ks * 32);
        float4 m4[4];
        #pragma unroll
        for (int jt = 0; jt < 4; ++jt)
            m4[jt] = *(const float4*)(mbase + k0 + jt * 16);

        // ---- S^T tile: rows j = jt*16 + quad*4 + reg, col i = l15 ----
        f32x4 sacc[4];
        #pragma unroll
        for (int jt = 0; jt < 4; ++jt) sacc[jt] = zz;
        #pragma unroll
        for (int jt = 0; jt < 4; ++jt)
            #pragma unroll
            for (int ks = 0; ks < 2; ++ks)
                sacc[jt] = __builtin_amdgcn_mfma_f32_16x16x32_bf16(
                    kf[jt][ks], qf[ks], sacc[jt], 0, 0, 0);

        // ---- mask + online softmax (per-lane row state for i = l15) ----
        float sv[4][4];
        float mx = -INFINITY;
        #pragma unroll
        for (int jt = 0; jt < 4; ++jt) {
            float mm[4] = {m4[jt].x, m4[jt].y, m4[jt].z, m4[jt].w};
            #pragma unroll
            for (int r = 0; r < 4; ++r) {
                sv[jt][r] = sacc[jt][r] * mm[r];
                mx = fmaxf(mx, sv[jt][r]);
            }
        }
        mx = fmaxf(mx, __shfl_xor(mx, 16));
        mx = fmaxf(mx, __shfl_xor(mx, 32));
        float mn = fmaxf(rm, mx);
        float al = __expf(rm - mn);   // first iter: exp(-inf) = 0
        rm = mn; rZ *= al; rZm *= al;
        #pragma unroll
        for (int dt = 0; dt < 4; ++dt)
            #pragma unroll
            for (int r = 0; r < 4; ++r) oacc[dt][r] *= al;

        float z = 0.f, zm = 0.f;
        #pragma unroll
        for (int jt = 0; jt < 4; ++jt) {
            float mm[4] = {m4[jt].x, m4[jt].y, m4[jt].z, m4[jt].w};
            float p[4];
            #pragma unroll
            for (int r = 0; r < 4; ++r) {
                float e = __expf(sv[jt][r] - mn);
                float pm = e * mm[r];
                z += e; zm += pm; p[r] = pm;
            }
            unsigned lo = (unsigned)f2bf(p[0]) | ((unsigned)f2bf(p[1]) << 16);
            unsigned hi = (unsigned)f2bf(p[2]) | ((unsigned)f2bf(p[3]) << 16);
            uint2 pk; pk.x = lo; pk.y = hi;
            *(uint2*)&Ps[wave][l15][jt * 16 + quad * 4] = pk;   // P[i][j] 4 contig j
        }
        z  += __shfl_xor(z, 16);  z  += __shfl_xor(z, 32);
        zm += __shfl_xor(zm, 16); zm += __shfl_xor(zm, 32);
        rZ += z; rZm += zm;

        // ---- P fragments (B[n=i][k=j]) from wave-private LDS, no barrier ----
        bf16x8 pf[2];
        #pragma unroll
        for (int ks = 0; ks < 2; ++ks)
            pf[ks] = *(const bf16x8*)&Ps[wave][l15][ks * 32 + quad * 8];
        #pragma unroll
        for (int dt = 0; dt < 4; ++dt)
            #pragma unroll
            for (int ks = 0; ks < 2; ++ks)
                oacc[dt] = __builtin_amdgcn_mfma_f32_16x16x32_bf16(
                    vf[dt][ks], pf[ks], oacc[dt], 0, 0, 0);
    }

    // ---- epilogue: O^T regs (row=d, col=i) -> O[b,q0+i][h*64+d] ----
    float inv = 1.0f / (rZm + 1e-8f * rZ);
    #pragma unroll
    for (int dt = 0; dt < 4; ++dt) {
        ushort4 o4;
        o4.x = f2bf(oacc[dt][0] * inv);
        o4.y = f2bf(oacc[dt][1] * inv);
        o4.z = f2bf(oacc[dt][2] * inv);
        o4.w = f2bf(oacc[dt][3] * inv);
        *(ushort4*)(O + (size_t)(b * S_LEN + iRow) * DMODEL + h * HDIM + dt * 16 + quad * 4) = o4;
    }
}

// ---------------- launch ----------------
extern "C" void kernel_launch(void* const* d_in, const int* in_sizes, int n_in,
                              void* d_out, int out_size, void* d_ws, size_t ws_size,
                              hipStream_t stream)
{
    const float* gene_emb = (const float*)d_in[0];
    const float* expr_emb = (const float*)d_in[1];
    const float* M        = (const float*)d_in[2];
    const float* g_wq = (const float*)d_in[3];
    const float* g_wk = (const float*)d_in[4];
    const float* g_wv = (const float*)d_in[5];
    const float* g_wo = (const float*)d_in[6];
    const float* g_bq = (const float*)d_in[7];
    const float* g_bk = (const float*)d_in[8];
    const float* g_bv = (const float*)d_in[9];
    const float* g_bo = (const float*)d_in[10];
    const float* e_wf = (const float*)d_in[11];
    const float* e_bf = (const float*)d_in[12];
    const float* e_wq = (const float*)d_in[13];
    const float* e_wk = (const float*)d_in[14];
    const float* e_wv = (const float*)d_in[15];
    const float* e_wo = (const float*)d_in[16];
    const float* e_bq = (const float*)d_in[17];
    const float* e_bk = (const float*)d_in[18];
    const float* e_bv = (const float*)d_in[19];
    const float* e_bo = (const float*)d_in[20];
    const float* ln_g1_w = (const float*)d_in[21];
    const float* ln_g2_w = (const float*)d_in[22];
    const float* ln_e1_w = (const float*)d_in[23];
    const float* ln_e2_w = (const float*)d_in[24];
    const float* ln_g1_b = (const float*)d_in[25];
    const float* ln_g2_b = (const float*)d_in[26];
    const float* ln_e1_b = (const float*)d_in[27];
    const float* ln_e2_b = (const float*)d_in[28];
    const float* fg_w1 = (const float*)d_in[29];
    const float* fg_b1 = (const float*)d_in[30];
    const float* fg_w2 = (const float*)d_in[31];
    const float* fg_b2 = (const float*)d_in[32];
    const float* fe_w1 = (const float*)d_in[33];
    const float* fe_b1 = (const float*)d_in[34];
    const float* fe_w2 = (const float*)d_in[35];
    const float* fe_b2 = (const float*)d_in[36];

    float* out_gene = (float*)d_out;
    float* out_expr = out_gene + (size_t)NROWS * DMODEL;

    // ---- workspace (bytes). proven ws >= 56 MB (round-1 layout). ----
    char* ws = (char*)d_ws;
    const size_t MB1 = 1024 * 1024;
    unsigned short* bufA16  = (unsigned short*)(ws + 0 * MB1);   // 0-4
    unsigned short* bufAt16 = (unsigned short*)(ws + 4 * MB1);   // 4-8 (attn out)
    unsigned short* bufCat  = (unsigned short*)(ws + 4 * MB1);   // 4-12 (expr only, pre-attn)
    unsigned short* bufQKV  = (unsigned short*)(ws + 12 * MB1);  // 12-24 gene [4096][1536]
    unsigned short* bufQKe  = (unsigned short*)(ws + 12 * MB1);  // 12-20 expr [4096][1024]
    unsigned short* bufV16  = (unsigned short*)(ws + 20 * MB1);  // 20-24 expr V [4096][512]
    unsigned short* bufVt   = (unsigned short*)(ws + 24 * MB1);  // 24-28 [16][64][2048]
    float*          bufX    = (float*)(ws + 28 * MB1);           // 28-36 fp32 residual
    unsigned short* bufH16  = (unsigned short*)(ws + 12 * MB1);  // 12-28 FFN hidden
    char* wp = ws + 36 * MB1;                                    // 36-49 weights
    unsigned short* gwq_t = (unsigned short*)(wp);               wp += 512 * 512 * 2;
    unsigned short* gwk_t = (unsigned short*)(wp);               wp += 512 * 512 * 2;
    unsigned short* gwv_t = (unsigned short*)(wp);               wp += 512 * 512 * 2;
    unsigned short* gwo_t = (unsigned short*)(wp);               wp += 512 * 512 * 2;
    unsigned short* ewf_t = (unsigned short*)(wp);               wp += 1024 * 512 * 2;
    unsigned short* ewq_t = (unsigned short*)(wp);               wp += 512 * 512 * 2;
    unsigned short* ewk_t = (unsigned short*)(wp);               wp += 512 * 512 * 2;
    unsigned short* ewv_t = (unsigned short*)(wp);               wp += 512 * 512 * 2;
    unsigned short* ewo_t = (unsigned short*)(wp);               wp += 512 * 512 * 2;
    unsigned short* fgw1_t = (unsigned short*)(wp);              wp += 512 * 2048 * 2;
    unsigned short* fgw2_t = (unsigned short*)(wp);              wp += 2048 * 512 * 2;
    unsigned short* few1_t = (unsigned short*)(wp);              wp += 512 * 2048 * 2;
    unsigned short* few2_t = (unsigned short*)(wp);              wp += 2048 * 512 * 2;
    float* biasg = (float*)wp;                                   wp += 1536 * 4;
    float* biase = (float*)wp;                                   wp += 1024 * 4;

    dim3 blk(256);
    dim3 ln_grid(NROWS);
    dim3 g512(4, 32);
    dim3 g1024(8, 32);
    dim3 g1536(12, 32);
    dim3 g2048(16, 32);
    dim3 attn_grid(S_LEN / 64, 16);
    dim3 vt_grid(S_LEN / 64, NHEAD, 2);

    // ---- weight prep ----
    wcast_t<<<dim3(16, 16), blk, 0, stream>>>(g_wq, gwq_t, 512, 512);
    wcast_t<<<dim3(16, 16), blk, 0, stream>>>(g_wk, gwk_t, 512, 512);
    wcast_t<<<dim3(16, 16), blk, 0, stream>>>(g_wv, gwv_t, 512, 512);
    wcast_t<<<dim3(16, 16), blk, 0, stream>>>(g_wo, gwo_t, 512, 512);
    wcast_t<<<dim3(16, 32), blk, 0, stream>>>(e_wf, ewf_t, 1024, 512);
    wcast_t<<<dim3(16, 16), blk, 0, stream>>>(e_wq, ewq_t, 512, 512);
    wcast_t<<<dim3(16, 16), blk, 0, stream>>>(e_wk, ewk_t, 512, 512);
    wcast_t<<<dim3(16, 16), blk, 0, stream>>>(e_wv, ewv_t, 512, 512);
    wcast_t<<<dim3(16, 16), blk, 0, stream>>>(e_wo, ewo_t, 512, 512);
    wcast_t<<<dim3(64, 16), blk, 0, stream>>>(fg_w1, fgw1_t, 512, 2048);
    wcast_t<<<dim3(16, 64), blk, 0, stream>>>(fg_w2, fgw2_t, 2048, 512);
    wcast_t<<<dim3(64, 16), blk, 0, stream>>>(fe_w1, few1_t, 512, 2048);
    wcast_t<<<dim3(16, 64), blk, 0, stream>>>(fe_w2, few2_t, 2048, 512);
    pack_bias<<<dim3(6), blk, 0, stream>>>(g_bq, g_bk, g_bv, biasg, 1536);
    pack_bias<<<dim3(4), blk, 0, stream>>>(e_bq, e_bk, e_bk, biase, 1024);

    // ---------------- gene branch ----------------
    ln_kernel<<<ln_grid, blk, 0, stream>>>(gene_emb, ln_g1_w, ln_g1_b, bufA16, 512);
    gemm_mfma<<<g1536, blk, 0, stream>>>(bufA16, 512, gwq_t, biasg, nullptr, nullptr, nullptr, bufQKV, 512, 1536, 0);
    vtrans<<<vt_grid, blk, 0, stream>>>(bufQKV + 1024, 1536, bufVt);
    attn_mfma<<<attn_grid, blk, 0, stream>>>(bufQKV, 1536, bufQKV + 512, 1536, bufVt, M, bufAt16);
    gemm_mfma<<<g512, blk, 0, stream>>>(bufAt16, 512, gwo_t, g_bo, gene_emb, nullptr, bufX, nullptr, 512, 512, 0);
    ln_kernel<<<ln_grid, blk, 0, stream>>>(bufX, ln_g2_w, ln_g2_b, bufA16, 512);
    gemm_mfma<<<g2048, blk, 0, stream>>>(bufA16, 512, fgw1_t, fg_b1, nullptr, nullptr, nullptr, bufH16, 512, 2048, 1);
    gemm_mfma<<<g512, blk, 0, stream>>>(bufH16, 2048, fgw2_t, fg_b2, bufX, bufA16, out_gene, nullptr, 2048, 512, 0);

    // ---------------- expr branch ----------------
    cast_strided<<<ln_grid, blk, 0, stream>>>(gene_emb, bufCat, 1024);
    ln_kernel<<<ln_grid, blk, 0, stream>>>(expr_emb, ln_e1_w, ln_e1_b, bufCat + 512, 1024);
    gemm_mfma<<<g512, blk, 0, stream>>>(bufCat, 1024, ewf_t, e_bf, nullptr, nullptr, nullptr, bufA16, 1024, 512, 0);
    gemm_mfma<<<g1024, blk, 0, stream>>>(bufA16, 512, ewq_t, biase, nullptr, nullptr, nullptr, bufQKe, 512, 1024, 0);
    gemm_mfma<<<g512, blk, 0, stream>>>(bufCat + 512, 1024, ewv_t, e_bv, nullptr, nullptr, nullptr, bufV16, 512, 512, 0);
    vtrans<<<vt_grid, blk, 0, stream>>>(bufV16, 512, bufVt);
    attn_mfma<<<attn_grid, blk, 0, stream>>>(bufQKe, 1024, bufQKe + 512, 1024, bufVt, M, bufAt16);
    gemm_mfma<<<g512, blk, 0, stream>>>(bufAt16, 512, ewo_t, e_bo, expr_emb, nullptr, bufX, nullptr, 512, 512, 0);
    ln_kernel<<<ln_grid, blk, 0, stream>>>(bufX, ln_e2_w, ln_e2_b, bufA16, 512);
    gemm_mfma<<<g2048, blk, 0, stream>>>(bufA16, 512, few1_t, fe_b1, nullptr, nullptr, nullptr, bufH16, 512, 2048, 1);
    gemm_mfma<<<g512, blk, 0, stream>>>(bufH16, 2048, few2_t, fe_b2, bufX, bufA16, out_expr, nullptr, 2048, 512, 0);
}

// Round 5
// 762.126 us; speedup vs baseline: 10.9159x; 1.1280x over previous
//
#include <hip/hip_runtime.h>
#include <math.h>

// Problem constants
#define S_LEN 2048
#define DMODEL 512
#define NROWS 4096   // B*S
#define NHEAD 8
#define HDIM 64

typedef __attribute__((ext_vector_type(8))) __bf16 bf16x8;
typedef __attribute__((ext_vector_type(4))) float f32x4;

__device__ inline float bf2f(unsigned short h) {
    unsigned u = ((unsigned)h) << 16;
    return __builtin_bit_cast(float, u);
}
__device__ inline unsigned short f2bf(float f) {
    unsigned u = __builtin_bit_cast(unsigned, f);
    return (unsigned short)((u + 0x7fffu + ((u >> 16) & 1u)) >> 16);
}

// ---------------- weight cast + transpose: Wt[mo][k] = bf16(W[k][mo]) ------
__global__ __launch_bounds__(256) void wcast_t(
    const float* __restrict__ W, unsigned short* __restrict__ Wt, int K, int Mo)
{
    __shared__ float t[32][33];
    const int bx = blockIdx.x * 32;   // Mo
    const int by = blockIdx.y * 32;   // K
    const int tx = threadIdx.x & 31, ty = threadIdx.x >> 5;  // ty 0..7
    #pragma unroll
    for (int r = 0; r < 4; ++r)
        t[ty + 8 * r][tx] = W[(size_t)(by + ty + 8 * r) * Mo + bx + tx];
    __syncthreads();
    #pragma unroll
    for (int r = 0; r < 4; ++r)
        Wt[(size_t)(bx + ty + 8 * r) * K + by + tx] = f2bf(t[tx][ty + 8 * r]);
}

// ---------------- pack up to 3 bias vectors (512 each) into one ----------
__global__ __launch_bounds__(256) void pack_bias(
    const float* __restrict__ b1, const float* __restrict__ b2,
    const float* __restrict__ b3, float* __restrict__ dst, int n)
{
    int t = blockIdx.x * 256 + threadIdx.x;
    if (t >= n) return;
    float v = (t < 512) ? b1[t] : (t < 1024) ? b2[t - 512] : b3[t - 1024];
    dst[t] = v;
}

// ---------------- strided fp32 -> bf16 cast (gene_emb -> concat left) ------
__global__ __launch_bounds__(256) void cast_strided(
    const float* __restrict__ in, unsigned short* __restrict__ out, int ostride)
{
    const int row = blockIdx.x, t = threadIdx.x;
    out[(size_t)row * ostride + t]       = f2bf(in[(size_t)row * DMODEL + t]);
    out[(size_t)row * ostride + t + 256] = f2bf(in[(size_t)row * DMODEL + t + 256]);
}

// ---------------- LayerNorm: fp32 in, bf16 out (strided) ----------------
__global__ __launch_bounds__(256) void ln_kernel(
    const float* __restrict__ x, const float* __restrict__ w,
    const float* __restrict__ b, unsigned short* __restrict__ y, int ostride)
{
    __shared__ float red[8];
    const int row = blockIdx.x;
    const float* xr = x + (size_t)row * DMODEL;
    const int t = threadIdx.x;
    float v0 = xr[t];
    float v1 = xr[t + 256];
    float s  = v0 + v1;
    float sq = v0 * v0 + v1 * v1;
    #pragma unroll
    for (int o = 32; o > 0; o >>= 1) {
        s  += __shfl_down(s, o);
        sq += __shfl_down(sq, o);
    }
    int wid = t >> 6, lane = t & 63;
    if (lane == 0) { red[wid] = s; red[4 + wid] = sq; }
    __syncthreads();
    float mean = (red[0] + red[1] + red[2] + red[3]) * (1.0f / 512.0f);
    float msq  = (red[4] + red[5] + red[6] + red[7]) * (1.0f / 512.0f);
    float var  = msq - mean * mean;
    float rs   = rsqrtf(var + 1e-5f);
    y[(size_t)row * ostride + t]       = f2bf((v0 - mean) * rs * w[t] + b[t]);
    y[(size_t)row * ostride + t + 256] = f2bf((v1 - mean) * rs * w[t + 256] + b[t + 256]);
}

// ---------------- V transpose: Vt[(b*8+h)*64 + d][s] = V[b*2048+s][h*64+d] --
__global__ __launch_bounds__(256) void vtrans(
    const unsigned short* __restrict__ V, int ldv, unsigned short* __restrict__ Vt)
{
    __shared__ unsigned short t[64][72];
    const int s0 = blockIdx.x * 64, h = blockIdx.y, b = blockIdx.z;
    const int tid = threadIdx.x;
    {
        const int r = tid >> 2, c = (tid & 3) * 16;
        const unsigned short* src = V + (size_t)(b * S_LEN + s0 + r) * ldv + h * 64 + c;
        *(int4*)&t[r][c]     = *(const int4*)(src);
        *(int4*)&t[r][c + 8] = *(const int4*)(src + 8);
    }
    __syncthreads();
    {
        const int d = tid >> 2, s = (tid & 3) * 16;
        unsigned short* dst = Vt + ((size_t)((b * 8 + h) * 64 + d)) * S_LEN + s0 + s;
        unsigned short tmp[16];
        #pragma unroll
        for (int e = 0; e < 16; ++e) tmp[e] = t[s + e][d];
        *(int4*)dst       = *(int4*)&tmp[0];
        *(int4*)(dst + 8) = *(int4*)&tmp[8];
    }
}

// ---------------- bf16 MFMA GEMM, 128x128 tile, BK=32 ----------------
__global__ __launch_bounds__(256) void gemm_mfma(
    const unsigned short* __restrict__ A, int lda,
    const unsigned short* __restrict__ Bt,
    const float* __restrict__ bias,
    const float* __restrict__ R1,
    const unsigned short* __restrict__ R2,
    float* __restrict__ Cf, unsigned short* __restrict__ Cb,
    int K, int Mo, int dogelu)
{
    __shared__ __align__(16) unsigned short As[128 * 32];
    __shared__ __align__(16) unsigned short Bs[128 * 32];
    const int tid = threadIdx.x;
    const int wave = tid >> 6, lane = tid & 63;
    const int wr = wave >> 1, wc = wave & 1;
    const int row0 = blockIdx.y * 128, col0 = blockIdx.x * 128;
    const int l15 = lane & 15, q = lane >> 4;

    f32x4 acc[4][4];
    const f32x4 zz = {0.f, 0.f, 0.f, 0.f};
    #pragma unroll
    for (int i = 0; i < 4; ++i)
        #pragma unroll
        for (int j = 0; j < 4; ++j) acc[i][j] = zz;

    for (int k0 = 0; k0 < K; k0 += 32) {
        #pragma unroll
        for (int r = 0; r < 2; ++r) {
            int idx = r * 256 + tid;
            int row = idx >> 2, kc = idx & 3;
            *(int4*)&As[row * 32 + kc * 8] =
                *(const int4*)&A[(size_t)(row0 + row) * lda + k0 + kc * 8];
            *(int4*)&Bs[row * 32 + kc * 8] =
                *(const int4*)&Bt[(size_t)(col0 + row) * K + k0 + kc * 8];
        }
        __syncthreads();
        bf16x8 af[4], bfr[4];
        #pragma unroll
        for (int fi = 0; fi < 4; ++fi)
            af[fi] = *(const bf16x8*)&As[(wr * 64 + fi * 16 + l15) * 32 + q * 8];
        #pragma unroll
        for (int fj = 0; fj < 4; ++fj)
            bfr[fj] = *(const bf16x8*)&Bs[(wc * 64 + fj * 16 + l15) * 32 + q * 8];
        #pragma unroll
        for (int fi = 0; fi < 4; ++fi)
            #pragma unroll
            for (int fj = 0; fj < 4; ++fj)
                acc[fi][fj] = __builtin_amdgcn_mfma_f32_16x16x32_bf16(
                    af[fi], bfr[fj], acc[fi][fj], 0, 0, 0);
        __syncthreads();
    }

    #pragma unroll
    for (int fi = 0; fi < 4; ++fi) {
        #pragma unroll
        for (int reg = 0; reg < 4; ++reg) {
            int row = row0 + wr * 64 + fi * 16 + q * 4 + reg;
            #pragma unroll
            for (int fj = 0; fj < 4; ++fj) {
                int col = col0 + wc * 64 + fj * 16 + l15;
                float v = acc[fi][fj][reg] + bias[col];
                if (dogelu) v = 0.5f * v * (1.0f + erff(v * 0.70710678118654752f));
                size_t off = (size_t)row * Mo + col;
                if (R1) v += R1[off];
                if (R2) v += bf2f(R2[off]);
                if (Cb) Cb[off] = f2bf(v);
                else    Cf[off] = v;
            }
        }
    }
}

// ---------------- bf16 MFMA GEMM, 64x64 tile (for skinny Mo) ----------------
// 4 waves, each owns 16 rows x 64 cols. Grid 2x the CU coverage of 128-tile.
__global__ __launch_bounds__(256) void gemm_mfma64(
    const unsigned short* __restrict__ A, int lda,
    const unsigned short* __restrict__ Bt,
    const float* __restrict__ bias,
    const float* __restrict__ R1,
    const unsigned short* __restrict__ R2,
    float* __restrict__ Cf, unsigned short* __restrict__ Cb,
    int K, int Mo, int dogelu)
{
    __shared__ __align__(16) unsigned short As[64 * 32];
    __shared__ __align__(16) unsigned short Bs[64 * 32];
    const int tid = threadIdx.x;
    const int wave = tid >> 6, lane = tid & 63;
    const int row0 = blockIdx.y * 64, col0 = blockIdx.x * 64;
    const int l15 = lane & 15, q = lane >> 4;
    const int srow = tid >> 2, skc = tid & 3;

    f32x4 acc[4];
    const f32x4 zz = {0.f, 0.f, 0.f, 0.f};
    #pragma unroll
    for (int j = 0; j < 4; ++j) acc[j] = zz;

    for (int k0 = 0; k0 < K; k0 += 32) {
        *(int4*)&As[srow * 32 + skc * 8] =
            *(const int4*)&A[(size_t)(row0 + srow) * lda + k0 + skc * 8];
        *(int4*)&Bs[srow * 32 + skc * 8] =
            *(const int4*)&Bt[(size_t)(col0 + srow) * K + k0 + skc * 8];
        __syncthreads();
        bf16x8 af = *(const bf16x8*)&As[(wave * 16 + l15) * 32 + q * 8];
        bf16x8 bfr[4];
        #pragma unroll
        for (int fj = 0; fj < 4; ++fj)
            bfr[fj] = *(const bf16x8*)&Bs[(fj * 16 + l15) * 32 + q * 8];
        #pragma unroll
        for (int fj = 0; fj < 4; ++fj)
            acc[fj] = __builtin_amdgcn_mfma_f32_16x16x32_bf16(af, bfr[fj], acc[fj], 0, 0, 0);
        __syncthreads();
    }

    #pragma unroll
    for (int reg = 0; reg < 4; ++reg) {
        int row = row0 + wave * 16 + q * 4 + reg;
        #pragma unroll
        for (int fj = 0; fj < 4; ++fj) {
            int col = col0 + fj * 16 + l15;
            float v = acc[fj][reg] + bias[col];
            if (dogelu) v = 0.5f * v * (1.0f + erff(v * 0.70710678118654752f));
            size_t off = (size_t)row * Mo + col;
            if (R1) v += R1[off];
            if (R2) v += bf2f(R2[off]);
            if (Cb) Cb[off] = f2bf(v);
            else    Cf[off] = v;
        }
    }
}

// ---------------- MFMA flash attention, split-K over S ----------------
// blockIdx.z = p selects S-chunk [p*1024, (p+1)*1024). Each wave owns 16
// q-rows; per-lane online-softmax state; writes unnormalized partial O^T
// (bf16) + stats (m, Z, Zm) for the combine pass. M tiles are prefetched
// one iteration ahead (HBM-latency loads).
__global__ __launch_bounds__(256) void attn_mfma_split(
    const unsigned short* __restrict__ Q, int ldq,
    const unsigned short* __restrict__ Kp, int ldk,
    const unsigned short* __restrict__ Vt,   // [16 bh][64 d][2048 s]
    const float* __restrict__ M,
    unsigned short* __restrict__ Opart,      // [2][16][2048][64] bf16
    float* __restrict__ stats)               // [2][16][2048][4] f32
{
    __shared__ unsigned short Ps[4][16][72];
    const int bh = blockIdx.y, b = bh >> 3, h = bh & 7;
    const int q0 = blockIdx.x * 64;
    const int p = blockIdx.z;
    const int tid = threadIdx.x, wave = tid >> 6, lane = tid & 63;
    const int l15 = lane & 15, quad = lane >> 4;
    const int iRow = q0 + wave * 16 + l15;   // q index within batch
    const int kBeg = p * (S_LEN / 2), kEnd = kBeg + (S_LEN / 2);

    // Q fragments (B-operand), pre-scaled by 1/8 (exact in bf16)
    bf16x8 qf[2];
    {
        const unsigned short* qp = Q + (size_t)(b * S_LEN + iRow) * ldq + h * HDIM + quad * 8;
        #pragma unroll
        for (int ks = 0; ks < 2; ++ks) {
            union { bf16x8 v; unsigned short u[8]; } tq;
            tq.v = *(const bf16x8*)(qp + ks * 32);
            #pragma unroll
            for (int e = 0; e < 8; ++e) tq.u[e] = f2bf(bf2f(tq.u[e]) * 0.125f);
            qf[ks] = tq.v;
        }
    }

    float rm = -INFINITY, rZ = 0.f, rZm = 0.f;
    f32x4 oacc[4];
    const f32x4 zz = {0.f, 0.f, 0.f, 0.f};
    #pragma unroll
    for (int dt = 0; dt < 4; ++dt) oacc[dt] = zz;

    const unsigned short* kbase = Kp + (size_t)(b * S_LEN + l15) * ldk + h * HDIM + quad * 8;
    const unsigned short* vbase = Vt + ((size_t)(bh * 64 + l15)) * S_LEN + quad * 8;
    const float* mbase = M + (size_t)b * S_LEN * S_LEN + (size_t)iRow * S_LEN + quad * 4;

    // prefetch first M tile
    float4 m4n[4];
    #pragma unroll
    for (int jt = 0; jt < 4; ++jt)
        m4n[jt] = *(const float4*)(mbase + kBeg + jt * 16);

    for (int k0 = kBeg; k0 < kEnd; k0 += 64) {
        float4 m4[4];
        #pragma unroll
        for (int jt = 0; jt < 4; ++jt) m4[jt] = m4n[jt];
        if (k0 + 64 < kEnd) {
            #pragma unroll
            for (int jt = 0; jt < 4; ++jt)
                m4n[jt] = *(const float4*)(mbase + k0 + 64 + jt * 16);
        }

        bf16x8 kf[4][2], vf[4][2];
        #pragma unroll
        for (int mt = 0; mt < 4; ++mt)
            #pragma unroll
            for (int ks = 0; ks < 2; ++ks)
                kf[mt][ks] = *(const bf16x8*)(kbase + (size_t)(k0 + mt * 16) * ldk + ks * 32);
        #pragma unroll
        for (int dt = 0; dt < 4; ++dt)
            #pragma unroll
            for (int ks = 0; ks < 2; ++ks)
                vf[dt][ks] = *(const bf16x8*)(vbase + (size_t)(dt * 16) * S_LEN + k0 + ks * 32);

        // ---- S^T tile ----
        f32x4 sacc[4];
        #pragma unroll
        for (int jt = 0; jt < 4; ++jt) sacc[jt] = zz;
        #pragma unroll
        for (int jt = 0; jt < 4; ++jt)
            #pragma unroll
            for (int ks = 0; ks < 2; ++ks)
                sacc[jt] = __builtin_amdgcn_mfma_f32_16x16x32_bf16(
                    kf[jt][ks], qf[ks], sacc[jt], 0, 0, 0);

        // ---- mask + online softmax ----
        float sv[4][4];
        float mx = -INFINITY;
        #pragma unroll
        for (int jt = 0; jt < 4; ++jt) {
            float mm[4] = {m4[jt].x, m4[jt].y, m4[jt].z, m4[jt].w};
            #pragma unroll
            for (int r = 0; r < 4; ++r) {
                sv[jt][r] = sacc[jt][r] * mm[r];
                mx = fmaxf(mx, sv[jt][r]);
            }
        }
        mx = fmaxf(mx, __shfl_xor(mx, 16));
        mx = fmaxf(mx, __shfl_xor(mx, 32));
        float mn = fmaxf(rm, mx);
        float al = __expf(rm - mn);
        rm = mn; rZ *= al; rZm *= al;
        #pragma unroll
        for (int dt = 0; dt < 4; ++dt)
            #pragma unroll
            for (int r = 0; r < 4; ++r) oacc[dt][r] *= al;

        float z = 0.f, zm = 0.f;
        #pragma unroll
        for (int jt = 0; jt < 4; ++jt) {
            float mm[4] = {m4[jt].x, m4[jt].y, m4[jt].z, m4[jt].w};
            float pv[4];
            #pragma unroll
            for (int r = 0; r < 4; ++r) {
                float e = __expf(sv[jt][r] - mn);
                float pm = e * mm[r];
                z += e; zm += pm; pv[r] = pm;
            }
            unsigned lo = (unsigned)f2bf(pv[0]) | ((unsigned)f2bf(pv[1]) << 16);
            unsigned hi = (unsigned)f2bf(pv[2]) | ((unsigned)f2bf(pv[3]) << 16);
            uint2 pk; pk.x = lo; pk.y = hi;
            *(uint2*)&Ps[wave][l15][jt * 16 + quad * 4] = pk;
        }
        z  += __shfl_xor(z, 16);  z  += __shfl_xor(z, 32);
        zm += __shfl_xor(zm, 16); zm += __shfl_xor(zm, 32);
        rZ += z; rZm += zm;

        // ---- P fragments from wave-private LDS, no barrier ----
        bf16x8 pf[2];
        #pragma unroll
        for (int ks = 0; ks < 2; ++ks)
            pf[ks] = *(const bf16x8*)&Ps[wave][l15][ks * 32 + quad * 8];
        #pragma unroll
        for (int dt = 0; dt < 4; ++dt)
            #pragma unroll
            for (int ks = 0; ks < 2; ++ks)
                oacc[dt] = __builtin_amdgcn_mfma_f32_16x16x32_bf16(
                    vf[dt][ks], pf[ks], oacc[dt], 0, 0, 0);
    }

    // ---- write partials ----
    unsigned short* op = Opart + (((size_t)(p * 16 + bh) * S_LEN + iRow) * 64);
    #pragma unroll
    for (int dt = 0; dt < 4; ++dt) {
        ushort4 o4;
        o4.x = f2bf(oacc[dt][0]); o4.y = f2bf(oacc[dt][1]);
        o4.z = f2bf(oacc[dt][2]); o4.w = f2bf(oacc[dt][3]);
        *(ushort4*)(op + dt * 16 + quad * 4) = o4;
    }
    if (quad == 0) {
        float4 st; st.x = rm; st.y = rZ; st.z = rZm; st.w = 0.f;
        *(float4*)&stats[(((size_t)p * 16 + bh) * S_LEN + iRow) * 4] = st;
    }
}

// ---------------- combine the two split-K partials ----------------
__global__ __launch_bounds__(256) void attn_combine(
    const unsigned short* __restrict__ Opart, const float* __restrict__ stats,
    unsigned short* __restrict__ O)
{
    const int bh = blockIdx.y, b = bh >> 3, h = bh & 7;
    const int q0 = blockIdx.x * 64;
    const int tid = threadIdx.x;
    const int i = tid >> 2, dq = (tid & 3) * 16;
    const int qg = q0 + i;

    float4 s0 = *(const float4*)&stats[(((size_t)0 * 16 + bh) * S_LEN + qg) * 4];
    float4 s1 = *(const float4*)&stats[(((size_t)1 * 16 + bh) * S_LEN + qg) * 4];
    float ms = fmaxf(s0.x, s1.x);
    float w0 = __expf(s0.x - ms), w1 = __expf(s1.x - ms);
    float Z  = w0 * s0.y + w1 * s1.y;
    float Zm = w0 * s0.z + w1 * s1.z;
    float inv = 1.0f / (Zm + 1e-8f * Z);
    w0 *= inv; w1 *= inv;

    const unsigned short* p0 = Opart + (((size_t)0 * 16 + bh) * S_LEN + qg) * 64 + dq;
    const unsigned short* p1 = Opart + (((size_t)1 * 16 + bh) * S_LEN + qg) * 64 + dq;
    union { int4 v; unsigned short u[8]; } a0, a1, r;
    unsigned short* dst = O + (size_t)(b * S_LEN + qg) * DMODEL + h * HDIM + dq;
    #pragma unroll
    for (int half = 0; half < 2; ++half) {
        a0.v = *(const int4*)(p0 + half * 8);
        a1.v = *(const int4*)(p1 + half * 8);
        #pragma unroll
        for (int e = 0; e < 8; ++e)
            r.u[e] = f2bf(w0 * bf2f(a0.u[e]) + w1 * bf2f(a1.u[e]));
        *(int4*)(dst + half * 8) = r.v;
    }
}

// ---------------- launch ----------------
extern "C" void kernel_launch(void* const* d_in, const int* in_sizes, int n_in,
                              void* d_out, int out_size, void* d_ws, size_t ws_size,
                              hipStream_t stream)
{
    const float* gene_emb = (const float*)d_in[0];
    const float* expr_emb = (const float*)d_in[1];
    const float* M        = (const float*)d_in[2];
    const float* g_wq = (const float*)d_in[3];
    const float* g_wk = (const float*)d_in[4];
    const float* g_wv = (const float*)d_in[5];
    const float* g_wo = (const float*)d_in[6];
    const float* g_bq = (const float*)d_in[7];
    const float* g_bk = (const float*)d_in[8];
    const float* g_bv = (const float*)d_in[9];
    const float* g_bo = (const float*)d_in[10];
    const float* e_wf = (const float*)d_in[11];
    const float* e_bf = (const float*)d_in[12];
    const float* e_wq = (const float*)d_in[13];
    const float* e_wk = (const float*)d_in[14];
    const float* e_wv = (const float*)d_in[15];
    const float* e_wo = (const float*)d_in[16];
    const float* e_bq = (const float*)d_in[17];
    const float* e_bk = (const float*)d_in[18];
    const float* e_bv = (const float*)d_in[19];
    const float* e_bo = (const float*)d_in[20];
    const float* ln_g1_w = (const float*)d_in[21];
    const float* ln_g2_w = (const float*)d_in[22];
    const float* ln_e1_w = (const float*)d_in[23];
    const float* ln_e2_w = (const float*)d_in[24];
    const float* ln_g1_b = (const float*)d_in[25];
    const float* ln_g2_b = (const float*)d_in[26];
    const float* ln_e1_b = (const float*)d_in[27];
    const float* ln_e2_b = (const float*)d_in[28];
    const float* fg_w1 = (const float*)d_in[29];
    const float* fg_b1 = (const float*)d_in[30];
    const float* fg_w2 = (const float*)d_in[31];
    const float* fg_b2 = (const float*)d_in[32];
    const float* fe_w1 = (const float*)d_in[33];
    const float* fe_b1 = (const float*)d_in[34];
    const float* fe_w2 = (const float*)d_in[35];
    const float* fe_b2 = (const float*)d_in[36];

    float* out_gene = (float*)d_out;
    float* out_expr = out_gene + (size_t)NROWS * DMODEL;

    // ---- workspace (MB offsets), peak ~54.3 MB of the proven >=56 MB ----
    char* ws = (char*)d_ws;
    const size_t MB1 = 1024 * 1024;
    unsigned short* bufA16  = (unsigned short*)(ws + 0 * MB1);   // 0-4
    unsigned short* bufAt16 = (unsigned short*)(ws + 4 * MB1);   // 4-8 attn combined
    unsigned short* bufQKV  = (unsigned short*)(ws + 8 * MB1);   // 8-20 gene [4096][1536]
    unsigned short* bufQKe  = (unsigned short*)(ws + 8 * MB1);   // 8-16 expr [4096][1024]
    unsigned short* bufV16  = (unsigned short*)(ws + 16 * MB1);  // 16-20 expr V
    unsigned short* bufVt   = (unsigned short*)(ws + 20 * MB1);  // 20-24
    unsigned short* bufCat  = (unsigned short*)(ws + 24 * MB1);  // 24-32 expr concat (dead pre-attn)
    unsigned short* bufOp   = (unsigned short*)(ws + 24 * MB1);  // 24-32 attn O partials
    float*          bufSt   = (float*)(ws + 32 * MB1);           // 32-33 attn stats
    float*          bufX    = (float*)(ws + 33 * MB1);           // 33-41 fp32 residual
    unsigned short* bufH16  = (unsigned short*)(ws + 8 * MB1);   // 8-24 FFN hidden (aliases QKV+Vt)
    char* wp = ws + 41 * MB1;                                    // 41-54.3 weights
    unsigned short* gwq_t = (unsigned short*)(wp);               wp += 512 * 512 * 2;
    unsigned short* gwk_t = (unsigned short*)(wp);               wp += 512 * 512 * 2;
    unsigned short* gwv_t = (unsigned short*)(wp);               wp += 512 * 512 * 2;
    unsigned short* gwo_t = (unsigned short*)(wp);               wp += 512 * 512 * 2;
    unsigned short* ewf_t = (unsigned short*)(wp);               wp += 1024 * 512 * 2;
    unsigned short* ewq_t = (unsigned short*)(wp);               wp += 512 * 512 * 2;
    unsigned short* ewk_t = (unsigned short*)(wp);               wp += 512 * 512 * 2;
    unsigned short* ewv_t = (unsigned short*)(wp);               wp += 512 * 512 * 2;
    unsigned short* ewo_t = (unsigned short*)(wp);               wp += 512 * 512 * 2;
    unsigned short* fgw1_t = (unsigned short*)(wp);              wp += 512 * 2048 * 2;
    unsigned short* fgw2_t = (unsigned short*)(wp);              wp += 2048 * 512 * 2;
    unsigned short* few1_t = (unsigned short*)(wp);              wp += 512 * 2048 * 2;
    unsigned short* few2_t = (unsigned short*)(wp);              wp += 2048 * 512 * 2;
    float* biasg = (float*)wp;                                   wp += 1536 * 4;
    float* biase = (float*)wp;                                   wp += 1024 * 4;

    dim3 blk(256);
    dim3 ln_grid(NROWS);
    dim3 g512s(8, 64);    // 64x64 tiles, Mo=512 -> 512 blocks
    dim3 g1024(8, 32);
    dim3 g1536(12, 32);
    dim3 g2048(16, 32);
    dim3 attn_grid(S_LEN / 64, 16, 2);
    dim3 comb_grid(S_LEN / 64, 16);
    dim3 vt_grid(S_LEN / 64, NHEAD, 2);

    // ---- weight prep ----
    wcast_t<<<dim3(16, 16), blk, 0, stream>>>(g_wq, gwq_t, 512, 512);
    wcast_t<<<dim3(16, 16), blk, 0, stream>>>(g_wk, gwk_t, 512, 512);
    wcast_t<<<dim3(16, 16), blk, 0, stream>>>(g_wv, gwv_t, 512, 512);
    wcast_t<<<dim3(16, 16), blk, 0, stream>>>(g_wo, gwo_t, 512, 512);
    wcast_t<<<dim3(16, 32), blk, 0, stream>>>(e_wf, ewf_t, 1024, 512);
    wcast_t<<<dim3(16, 16), blk, 0, stream>>>(e_wq, ewq_t, 512, 512);
    wcast_t<<<dim3(16, 16), blk, 0, stream>>>(e_wk, ewk_t, 512, 512);
    wcast_t<<<dim3(16, 16), blk, 0, stream>>>(e_wv, ewv_t, 512, 512);
    wcast_t<<<dim3(16, 16), blk, 0, stream>>>(e_wo, ewo_t, 512, 512);
    wcast_t<<<dim3(64, 16), blk, 0, stream>>>(fg_w1, fgw1_t, 512, 2048);
    wcast_t<<<dim3(16, 64), blk, 0, stream>>>(fg_w2, fgw2_t, 2048, 512);
    wcast_t<<<dim3(64, 16), blk, 0, stream>>>(fe_w1, few1_t, 512, 2048);
    wcast_t<<<dim3(16, 64), blk, 0, stream>>>(fe_w2, few2_t, 2048, 512);
    pack_bias<<<dim3(6), blk, 0, stream>>>(g_bq, g_bk, g_bv, biasg, 1536);
    pack_bias<<<dim3(4), blk, 0, stream>>>(e_bq, e_bk, e_bk, biase, 1024);

    // ---------------- gene branch ----------------
    ln_kernel<<<ln_grid, blk, 0, stream>>>(gene_emb, ln_g1_w, ln_g1_b, bufA16, 512);
    gemm_mfma<<<g1536, blk, 0, stream>>>(bufA16, 512, gwq_t, biasg, nullptr, nullptr, nullptr, bufQKV, 512, 1536, 0);
    vtrans<<<vt_grid, blk, 0, stream>>>(bufQKV + 1024, 1536, bufVt);
    attn_mfma_split<<<attn_grid, blk, 0, stream>>>(bufQKV, 1536, bufQKV + 512, 1536, bufVt, M, bufOp, bufSt);
    attn_combine<<<comb_grid, blk, 0, stream>>>(bufOp, bufSt, bufAt16);
    gemm_mfma64<<<g512s, blk, 0, stream>>>(bufAt16, 512, gwo_t, g_bo, gene_emb, nullptr, bufX, nullptr, 512, 512, 0);
    ln_kernel<<<ln_grid, blk, 0, stream>>>(bufX, ln_g2_w, ln_g2_b, bufA16, 512);
    gemm_mfma<<<g2048, blk, 0, stream>>>(bufA16, 512, fgw1_t, fg_b1, nullptr, nullptr, nullptr, bufH16, 512, 2048, 1);
    gemm_mfma64<<<g512s, blk, 0, stream>>>(bufH16, 2048, fgw2_t, fg_b2, bufX, bufA16, out_gene, nullptr, 2048, 512, 0);

    // ---------------- expr branch ----------------
    cast_strided<<<ln_grid, blk, 0, stream>>>(gene_emb, bufCat, 1024);
    ln_kernel<<<ln_grid, blk, 0, stream>>>(expr_emb, ln_e1_w, ln_e1_b, bufCat + 512, 1024);
    gemm_mfma64<<<g512s, blk, 0, stream>>>(bufCat, 1024, ewf_t, e_bf, nullptr, nullptr, nullptr, bufA16, 1024, 512, 0);
    gemm_mfma<<<g1024, blk, 0, stream>>>(bufA16, 512, ewq_t, biase, nullptr, nullptr, nullptr, bufQKe, 512, 1024, 0);
    gemm_mfma64<<<g512s, blk, 0, stream>>>(bufCat + 512, 1024, ewv_t, e_bv, nullptr, nullptr, nullptr, bufV16, 512, 512, 0);
    vtrans<<<vt_grid, blk, 0, stream>>>(bufV16, 512, bufVt);
    attn_mfma_split<<<attn_grid, blk, 0, stream>>>(bufQKe, 1024, bufQKe + 512, 1024, bufVt, M, bufOp, bufSt);
    attn_combine<<<comb_grid, blk, 0, stream>>>(bufOp, bufSt, bufAt16);
    gemm_mfma64<<<g512s, blk, 0, stream>>>(bufAt16, 512, ewo_t, e_bo, expr_emb, nullptr, bufX, nullptr, 512, 512, 0);
    ln_kernel<<<ln_grid, blk, 0, stream>>>(bufX, ln_e2_w, ln_e2_b, bufA16, 512);
    gemm_mfma<<<g2048, blk, 0, stream>>>(bufA16, 512, few1_t, fe_b1, nullptr, nullptr, nullptr, bufH16, 512, 2048, 1);
    gemm_mfma64<<<g512s, blk, 0, stream>>>(bufH16, 2048, few2_t, fe_b2, bufX, bufA16, out_expr, nullptr, 2048, 512, 0);
}

// Round 6
// 562.446 us; speedup vs baseline: 14.7912x; 1.3550x over previous
//
#include <hip/hip_runtime.h>
#include <math.h>

// Problem constants
#define S_LEN 2048
#define DMODEL 512
#define NROWS 4096   // B*S
#define NHEAD 8
#define HDIM 64

typedef __attribute__((ext_vector_type(8))) __bf16 bf16x8;
typedef __attribute__((ext_vector_type(4))) float f32x4;

__device__ inline float bf2f(unsigned short h) {
    unsigned u = ((unsigned)h) << 16;
    return __builtin_bit_cast(float, u);
}
__device__ inline unsigned short f2bf(float f) {
    unsigned u = __builtin_bit_cast(unsigned, f);
    return (unsigned short)((u + 0x7fffu + ((u >> 16) & 1u)) >> 16);
}

// ---------------- weight cast + transpose: Wt[mo][k] = bf16(W[k][mo]) ------
__global__ __launch_bounds__(256) void wcast_t(
    const float* __restrict__ W, unsigned short* __restrict__ Wt, int K, int Mo)
{
    __shared__ float t[32][33];
    const int bx = blockIdx.x * 32;   // Mo
    const int by = blockIdx.y * 32;   // K
    const int tx = threadIdx.x & 31, ty = threadIdx.x >> 5;
    #pragma unroll
    for (int r = 0; r < 4; ++r)
        t[ty + 8 * r][tx] = W[(size_t)(by + ty + 8 * r) * Mo + bx + tx];
    __syncthreads();
    #pragma unroll
    for (int r = 0; r < 4; ++r)
        Wt[(size_t)(bx + ty + 8 * r) * K + by + tx] = f2bf(t[tx][ty + 8 * r]);
}

// 8 square 512x512 weights in one launch (blockIdx.z selects)
__global__ __launch_bounds__(256) void wcast_sq8(
    const float* w0, const float* w1, const float* w2, const float* w3,
    const float* w4, const float* w5, const float* w6, const float* w7,
    unsigned short* __restrict__ dst)
{
    const float* srcs[8] = {w0, w1, w2, w3, w4, w5, w6, w7};
    const float* __restrict__ W = srcs[blockIdx.z];
    unsigned short* __restrict__ Wt = dst + (size_t)blockIdx.z * 512 * 512;
    __shared__ float t[32][33];
    const int bx = blockIdx.x * 32, by = blockIdx.y * 32;
    const int tx = threadIdx.x & 31, ty = threadIdx.x >> 5;
    #pragma unroll
    for (int r = 0; r < 4; ++r)
        t[ty + 8 * r][tx] = W[(size_t)(by + ty + 8 * r) * 512 + bx + tx];
    __syncthreads();
    #pragma unroll
    for (int r = 0; r < 4; ++r)
        Wt[(size_t)(bx + ty + 8 * r) * 512 + by + tx] = f2bf(t[tx][ty + 8 * r]);
}

// pair of same-shape weights in one launch (dst contiguous, stride K*Mo)
__global__ __launch_bounds__(256) void wcast_t2(
    const float* wA, const float* wB, unsigned short* __restrict__ dst,
    int K, int Mo)
{
    const float* __restrict__ W = blockIdx.z ? wB : wA;
    unsigned short* __restrict__ Wt = dst + (size_t)blockIdx.z * K * Mo;
    __shared__ float t[32][33];
    const int bx = blockIdx.x * 32, by = blockIdx.y * 32;
    const int tx = threadIdx.x & 31, ty = threadIdx.x >> 5;
    #pragma unroll
    for (int r = 0; r < 4; ++r)
        t[ty + 8 * r][tx] = W[(size_t)(by + ty + 8 * r) * Mo + bx + tx];
    __syncthreads();
    #pragma unroll
    for (int r = 0; r < 4; ++r)
        Wt[(size_t)(bx + ty + 8 * r) * K + by + tx] = f2bf(t[tx][ty + 8 * r]);
}

// ---------------- pack up to 3 bias vectors (512 each) into one ----------
__global__ __launch_bounds__(256) void pack_bias(
    const float* __restrict__ b1, const float* __restrict__ b2,
    const float* __restrict__ b3, float* __restrict__ dst, int n)
{
    int t = blockIdx.x * 256 + threadIdx.x;
    if (t >= n) return;
    float v = (t < 512) ? b1[t] : (t < 1024) ? b2[t - 512] : b3[t - 1024];
    dst[t] = v;
}

// ---------------- strided fp32 -> bf16 cast (gene_emb -> concat left) ------
__global__ __launch_bounds__(256) void cast_strided(
    const float* __restrict__ in, unsigned short* __restrict__ out, int ostride)
{
    const int row = blockIdx.x, t = threadIdx.x;
    out[(size_t)row * ostride + t]       = f2bf(in[(size_t)row * DMODEL + t]);
    out[(size_t)row * ostride + t + 256] = f2bf(in[(size_t)row * DMODEL + t + 256]);
}

// ---------------- LayerNorm: fp32 in, bf16 out (strided) ----------------
__global__ __launch_bounds__(256) void ln_kernel(
    const float* __restrict__ x, const float* __restrict__ w,
    const float* __restrict__ b, unsigned short* __restrict__ y, int ostride)
{
    __shared__ float red[8];
    const int row = blockIdx.x;
    const float* xr = x + (size_t)row * DMODEL;
    const int t = threadIdx.x;
    float v0 = xr[t];
    float v1 = xr[t + 256];
    float s  = v0 + v1;
    float sq = v0 * v0 + v1 * v1;
    #pragma unroll
    for (int o = 32; o > 0; o >>= 1) {
        s  += __shfl_down(s, o);
        sq += __shfl_down(sq, o);
    }
    int wid = t >> 6, lane = t & 63;
    if (lane == 0) { red[wid] = s; red[4 + wid] = sq; }
    __syncthreads();
    float mean = (red[0] + red[1] + red[2] + red[3]) * (1.0f / 512.0f);
    float msq  = (red[4] + red[5] + red[6] + red[7]) * (1.0f / 512.0f);
    float var  = msq - mean * mean;
    float rs   = rsqrtf(var + 1e-5f);
    y[(size_t)row * ostride + t]       = f2bf((v0 - mean) * rs * w[t] + b[t]);
    y[(size_t)row * ostride + t + 256] = f2bf((v1 - mean) * rs * w[t + 256] + b[t + 256]);
}

// ---------------- V transpose: Vt[(b*8+h)*64 + d][s] = V[b*2048+s][h*64+d] --
__global__ __launch_bounds__(256) void vtrans(
    const unsigned short* __restrict__ V, int ldv, unsigned short* __restrict__ Vt)
{
    __shared__ unsigned short t[64][72];
    const int s0 = blockIdx.x * 64, h = blockIdx.y, b = blockIdx.z;
    const int tid = threadIdx.x;
    {
        const int r = tid >> 2, c = (tid & 3) * 16;
        const unsigned short* src = V + (size_t)(b * S_LEN + s0 + r) * ldv + h * 64 + c;
        *(int4*)&t[r][c]     = *(const int4*)(src);
        *(int4*)&t[r][c + 8] = *(const int4*)(src + 8);
    }
    __syncthreads();
    {
        const int d = tid >> 2, s = (tid & 3) * 16;
        unsigned short* dst = Vt + ((size_t)((b * 8 + h) * 64 + d)) * S_LEN + s0 + s;
        unsigned short tmp[16];
        #pragma unroll
        for (int e = 0; e < 16; ++e) tmp[e] = t[s + e][d];
        *(int4*)dst       = *(int4*)&tmp[0];
        *(int4*)(dst + 8) = *(int4*)&tmp[8];
    }
}

// ---------------- bf16 MFMA GEMM, 128x128 tile, BK=32 ----------------
__global__ __launch_bounds__(256) void gemm_mfma(
    const unsigned short* __restrict__ A, int lda,
    const unsigned short* __restrict__ Bt,
    const float* __restrict__ bias,
    const float* __restrict__ R1,
    const unsigned short* __restrict__ R2,
    float* __restrict__ Cf, unsigned short* __restrict__ Cb,
    int K, int Mo, int dogelu)
{
    __shared__ __align__(16) unsigned short As[128 * 32];
    __shared__ __align__(16) unsigned short Bs[128 * 32];
    const int tid = threadIdx.x;
    const int wave = tid >> 6, lane = tid & 63;
    const int wr = wave >> 1, wc = wave & 1;
    const int row0 = blockIdx.y * 128, col0 = blockIdx.x * 128;
    const int l15 = lane & 15, q = lane >> 4;

    f32x4 acc[4][4];
    const f32x4 zz = {0.f, 0.f, 0.f, 0.f};
    #pragma unroll
    for (int i = 0; i < 4; ++i)
        #pragma unroll
        for (int j = 0; j < 4; ++j) acc[i][j] = zz;

    for (int k0 = 0; k0 < K; k0 += 32) {
        #pragma unroll
        for (int r = 0; r < 2; ++r) {
            int idx = r * 256 + tid;
            int row = idx >> 2, kc = idx & 3;
            *(int4*)&As[row * 32 + kc * 8] =
                *(const int4*)&A[(size_t)(row0 + row) * lda + k0 + kc * 8];
            *(int4*)&Bs[row * 32 + kc * 8] =
                *(const int4*)&Bt[(size_t)(col0 + row) * K + k0 + kc * 8];
        }
        __syncthreads();
        bf16x8 af[4], bfr[4];
        #pragma unroll
        for (int fi = 0; fi < 4; ++fi)
            af[fi] = *(const bf16x8*)&As[(wr * 64 + fi * 16 + l15) * 32 + q * 8];
        #pragma unroll
        for (int fj = 0; fj < 4; ++fj)
            bfr[fj] = *(const bf16x8*)&Bs[(wc * 64 + fj * 16 + l15) * 32 + q * 8];
        #pragma unroll
        for (int fi = 0; fi < 4; ++fi)
            #pragma unroll
            for (int fj = 0; fj < 4; ++fj)
                acc[fi][fj] = __builtin_amdgcn_mfma_f32_16x16x32_bf16(
                    af[fi], bfr[fj], acc[fi][fj], 0, 0, 0);
        __syncthreads();
    }

    #pragma unroll
    for (int fi = 0; fi < 4; ++fi) {
        #pragma unroll
        for (int reg = 0; reg < 4; ++reg) {
            int row = row0 + wr * 64 + fi * 16 + q * 4 + reg;
            #pragma unroll
            for (int fj = 0; fj < 4; ++fj) {
                int col = col0 + wc * 64 + fj * 16 + l15;
                float v = acc[fi][fj][reg] + bias[col];
                if (dogelu) v = 0.5f * v * (1.0f + erff(v * 0.70710678118654752f));
                size_t off = (size_t)row * Mo + col;
                if (R1) v += R1[off];
                if (R2) v += bf2f(R2[off]);
                if (Cb) Cb[off] = f2bf(v);
                else    Cf[off] = v;
            }
        }
    }
}

// ---------------- bf16 MFMA GEMM, 64x64 tile (for skinny Mo) ----------------
__global__ __launch_bounds__(256) void gemm_mfma64(
    const unsigned short* __restrict__ A, int lda,
    const unsigned short* __restrict__ Bt,
    const float* __restrict__ bias,
    const float* __restrict__ R1,
    const unsigned short* __restrict__ R2,
    float* __restrict__ Cf, unsigned short* __restrict__ Cb,
    int K, int Mo, int dogelu)
{
    __shared__ __align__(16) unsigned short As[64 * 32];
    __shared__ __align__(16) unsigned short Bs[64 * 32];
    const int tid = threadIdx.x;
    const int wave = tid >> 6, lane = tid & 63;
    const int row0 = blockIdx.y * 64, col0 = blockIdx.x * 64;
    const int l15 = lane & 15, q = lane >> 4;
    const int srow = tid >> 2, skc = tid & 3;

    f32x4 acc[4];
    const f32x4 zz = {0.f, 0.f, 0.f, 0.f};
    #pragma unroll
    for (int j = 0; j < 4; ++j) acc[j] = zz;

    for (int k0 = 0; k0 < K; k0 += 32) {
        *(int4*)&As[srow * 32 + skc * 8] =
            *(const int4*)&A[(size_t)(row0 + srow) * lda + k0 + skc * 8];
        *(int4*)&Bs[srow * 32 + skc * 8] =
            *(const int4*)&Bt[(size_t)(col0 + srow) * K + k0 + skc * 8];
        __syncthreads();
        bf16x8 af = *(const bf16x8*)&As[(wave * 16 + l15) * 32 + q * 8];
        bf16x8 bfr[4];
        #pragma unroll
        for (int fj = 0; fj < 4; ++fj)
            bfr[fj] = *(const bf16x8*)&Bs[(fj * 16 + l15) * 32 + q * 8];
        #pragma unroll
        for (int fj = 0; fj < 4; ++fj)
            acc[fj] = __builtin_amdgcn_mfma_f32_16x16x32_bf16(af, bfr[fj], acc[fj], 0, 0, 0);
        __syncthreads();
    }

    #pragma unroll
    for (int reg = 0; reg < 4; ++reg) {
        int row = row0 + wave * 16 + q * 4 + reg;
        #pragma unroll
        for (int fj = 0; fj < 4; ++fj) {
            int col = col0 + fj * 16 + l15;
            float v = acc[fj][reg] + bias[col];
            if (dogelu) v = 0.5f * v * (1.0f + erff(v * 0.70710678118654752f));
            size_t off = (size_t)row * Mo + col;
            if (R1) v += R1[off];
            if (R2) v += bf2f(R2[off]);
            if (Cb) Cb[off] = f2bf(v);
            else    Cf[off] = v;
        }
    }
}

// ---------------- MFMA flash attention, split-K, LDS-staged tiles ----------
// K/V 64x64 tiles staged cooperatively (coalesced 128B-row loads, shared by
// all 4 waves); M staged per-wave via coalesced float4 + LDS round-trip.
// P aliases the (already-consumed) M region. All fragment reads are
// ds_read_b128 with stride-72/68 padding (uniform bank spread).
__global__ __launch_bounds__(256, 4) void attn_mfma_split(
    const unsigned short* __restrict__ Q, int ldq,
    const unsigned short* __restrict__ Kp, int ldk,
    const unsigned short* __restrict__ Vt,   // [16 bh][64 d][2048 s]
    const float* __restrict__ M,
    unsigned short* __restrict__ Opart,      // [2][16][2048][64] bf16
    float* __restrict__ stats)               // [2][16][2048][4] f32
{
    __shared__ __align__(16) unsigned short Ks[64 * 72];
    __shared__ __align__(16) unsigned short Vs[64 * 72];
    __shared__ __align__(16) float Ms[4][16 * 68];   // per-wave M; P aliases

    const int bh = blockIdx.y, b = bh >> 3, h = bh & 7;
    const int q0 = blockIdx.x * 64;
    const int p = blockIdx.z;
    const int tid = threadIdx.x, wave = tid >> 6, lane = tid & 63;
    const int l15 = lane & 15, quad = lane >> 4;
    const int iRow = q0 + wave * 16 + l15;
    const int kBeg = p * (S_LEN / 2), kEnd = kBeg + (S_LEN / 2);

    unsigned short* Ps = (unsigned short*)&Ms[wave][0];   // [16][72] shorts

    // Q fragments (B-operand), pre-scaled by 1/8 (exact in bf16)
    bf16x8 qf[2];
    {
        const unsigned short* qp = Q + (size_t)(b * S_LEN + iRow) * ldq + h * HDIM + quad * 8;
        #pragma unroll
        for (int ks = 0; ks < 2; ++ks) {
            union { bf16x8 v; unsigned short u[8]; } tq;
            tq.v = *(const bf16x8*)(qp + ks * 32);
            #pragma unroll
            for (int e = 0; e < 8; ++e) tq.u[e] = f2bf(bf2f(tq.u[e]) * 0.125f);
            qf[ks] = tq.v;
        }
    }

    float rm = -INFINITY, rZ = 0.f, rZm = 0.f;
    f32x4 oacc[4];
    const f32x4 zz = {0.f, 0.f, 0.f, 0.f};
    #pragma unroll
    for (int dt = 0; dt < 4; ++dt) oacc[dt] = zz;

    // staging addresses
    const int srow = tid >> 3;            // 0..31
    const int scol = (tid & 7) * 8;       // 0..56 shorts
    const unsigned short* kg = Kp + ((size_t)b * S_LEN) * ldk + h * HDIM + scol;
    const unsigned short* vg = Vt + ((size_t)bh * 64 + srow) * S_LEN + scol;
    const float* mg = M + (size_t)b * S_LEN * S_LEN + (size_t)(q0 + wave * 16) * S_LEN;

    for (int k0 = kBeg; k0 < kEnd; k0 += 64) {
        __syncthreads();   // all waves done with Ks/Vs (and own Ps) of prev iter
        // ---- stage K and V (coalesced 128B rows) ----
        int4 kv0 = *(const int4*)(kg + (size_t)(k0 + srow) * ldk);
        int4 kv1 = *(const int4*)(kg + (size_t)(k0 + srow + 32) * ldk);
        int4 vv0 = *(const int4*)(vg + k0);
        int4 vv1 = *(const int4*)(vg + 32 * S_LEN + k0);
        // ---- stage M (per-wave, 4 rows x 256B per inst) ----
        float4 mv[4];
        #pragma unroll
        for (int c = 0; c < 4; ++c)
            mv[c] = *(const float4*)(mg + (size_t)(c * 4 + quad) * S_LEN + k0 + l15 * 4);
        *(int4*)&Ks[srow * 72 + scol]        = kv0;
        *(int4*)&Ks[(srow + 32) * 72 + scol] = kv1;
        *(int4*)&Vs[srow * 72 + scol]        = vv0;
        *(int4*)&Vs[(srow + 32) * 72 + scol] = vv1;
        #pragma unroll
        for (int c = 0; c < 4; ++c)
            *(float4*)&Ms[wave][(c * 4 + quad) * 68 + l15 * 4] = mv[c];
        __syncthreads();

        // ---- M for my 16 q-rows (reg copy BEFORE Ps overwrites region) ----
        float4 m4[4];
        #pragma unroll
        for (int jt = 0; jt < 4; ++jt)
            m4[jt] = *(const float4*)&Ms[wave][l15 * 68 + jt * 16 + quad * 4];

        // ---- S^T tile from LDS K frags ----
        f32x4 sacc[4];
        #pragma unroll
        for (int jt = 0; jt < 4; ++jt) sacc[jt] = zz;
        #pragma unroll
        for (int jt = 0; jt < 4; ++jt) {
            bf16x8 kf0 = *(const bf16x8*)&Ks[(jt * 16 + l15) * 72 + quad * 8];
            bf16x8 kf1 = *(const bf16x8*)&Ks[(jt * 16 + l15) * 72 + 32 + quad * 8];
            sacc[jt] = __builtin_amdgcn_mfma_f32_16x16x32_bf16(kf0, qf[0], sacc[jt], 0, 0, 0);
            sacc[jt] = __builtin_amdgcn_mfma_f32_16x16x32_bf16(kf1, qf[1], sacc[jt], 0, 0, 0);
        }

        // ---- mask + online softmax (per-lane row state for i) ----
        float mx = -INFINITY;
        #pragma unroll
        for (int jt = 0; jt < 4; ++jt) {
            float mm[4] = {m4[jt].x, m4[jt].y, m4[jt].z, m4[jt].w};
            #pragma unroll
            for (int r = 0; r < 4; ++r) {
                sacc[jt][r] = sacc[jt][r] * mm[r];
                mx = fmaxf(mx, sacc[jt][r]);
            }
        }
        mx = fmaxf(mx, __shfl_xor(mx, 16));
        mx = fmaxf(mx, __shfl_xor(mx, 32));
        float mn = fmaxf(rm, mx);
        float al = __expf(rm - mn);
        rm = mn; rZ *= al; rZm *= al;
        #pragma unroll
        for (int dt = 0; dt < 4; ++dt)
            #pragma unroll
            for (int r = 0; r < 4; ++r) oacc[dt][r] *= al;

        float z = 0.f, zm = 0.f;
        #pragma unroll
        for (int jt = 0; jt < 4; ++jt) {
            float mm[4] = {m4[jt].x, m4[jt].y, m4[jt].z, m4[jt].w};
            float pv[4];
            #pragma unroll
            for (int r = 0; r < 4; ++r) {
                float e = __expf(sacc[jt][r] - mn);
                float pm = e * mm[r];
                z += e; zm += pm; pv[r] = pm;
            }
            unsigned lo = (unsigned)f2bf(pv[0]) | ((unsigned)f2bf(pv[1]) << 16);
            unsigned hi = (unsigned)f2bf(pv[2]) | ((unsigned)f2bf(pv[3]) << 16);
            uint2 pk; pk.x = lo; pk.y = hi;
            *(uint2*)&Ps[l15 * 72 + jt * 16 + quad * 4] = pk;
        }
        z  += __shfl_xor(z, 16);  z  += __shfl_xor(z, 32);
        zm += __shfl_xor(zm, 16); zm += __shfl_xor(zm, 32);
        rZ += z; rZm += zm;

        // ---- P frags (wave-private) + V frags from LDS; PV MFMA ----
        bf16x8 pf0 = *(const bf16x8*)&Ps[l15 * 72 + quad * 8];
        bf16x8 pf1 = *(const bf16x8*)&Ps[l15 * 72 + 32 + quad * 8];
        #pragma unroll
        for (int dt = 0; dt < 4; ++dt) {
            bf16x8 vf0 = *(const bf16x8*)&Vs[(dt * 16 + l15) * 72 + quad * 8];
            bf16x8 vf1 = *(const bf16x8*)&Vs[(dt * 16 + l15) * 72 + 32 + quad * 8];
            oacc[dt] = __builtin_amdgcn_mfma_f32_16x16x32_bf16(vf0, pf0, oacc[dt], 0, 0, 0);
            oacc[dt] = __builtin_amdgcn_mfma_f32_16x16x32_bf16(vf1, pf1, oacc[dt], 0, 0, 0);
        }
    }

    // ---- write partials ----
    unsigned short* op = Opart + (((size_t)(p * 16 + bh) * S_LEN + iRow) * 64);
    #pragma unroll
    for (int dt = 0; dt < 4; ++dt) {
        ushort4 o4;
        o4.x = f2bf(oacc[dt][0]); o4.y = f2bf(oacc[dt][1]);
        o4.z = f2bf(oacc[dt][2]); o4.w = f2bf(oacc[dt][3]);
        *(ushort4*)(op + dt * 16 + quad * 4) = o4;
    }
    if (quad == 0) {
        float4 st; st.x = rm; st.y = rZ; st.z = rZm; st.w = 0.f;
        *(float4*)&stats[(((size_t)p * 16 + bh) * S_LEN + iRow) * 4] = st;
    }
}

// ---------------- combine the two split-K partials ----------------
__global__ __launch_bounds__(256) void attn_combine(
    const unsigned short* __restrict__ Opart, const float* __restrict__ stats,
    unsigned short* __restrict__ O)
{
    const int bh = blockIdx.y, b = bh >> 3, h = bh & 7;
    const int q0 = blockIdx.x * 64;
    const int tid = threadIdx.x;
    const int i = tid >> 2, dq = (tid & 3) * 16;
    const int qg = q0 + i;

    float4 s0 = *(const float4*)&stats[(((size_t)0 * 16 + bh) * S_LEN + qg) * 4];
    float4 s1 = *(const float4*)&stats[(((size_t)1 * 16 + bh) * S_LEN + qg) * 4];
    float ms = fmaxf(s0.x, s1.x);
    float w0 = __expf(s0.x - ms), w1 = __expf(s1.x - ms);
    float Z  = w0 * s0.y + w1 * s1.y;
    float Zm = w0 * s0.z + w1 * s1.z;
    float inv = 1.0f / (Zm + 1e-8f * Z);
    w0 *= inv; w1 *= inv;

    const unsigned short* p0 = Opart + (((size_t)0 * 16 + bh) * S_LEN + qg) * 64 + dq;
    const unsigned short* p1 = Opart + (((size_t)1 * 16 + bh) * S_LEN + qg) * 64 + dq;
    union { int4 v; unsigned short u[8]; } a0, a1, r;
    unsigned short* dst = O + (size_t)(b * S_LEN + qg) * DMODEL + h * HDIM + dq;
    #pragma unroll
    for (int half = 0; half < 2; ++half) {
        a0.v = *(const int4*)(p0 + half * 8);
        a1.v = *(const int4*)(p1 + half * 8);
        #pragma unroll
        for (int e = 0; e < 8; ++e)
            r.u[e] = f2bf(w0 * bf2f(a0.u[e]) + w1 * bf2f(a1.u[e]));
        *(int4*)(dst + half * 8) = r.v;
    }
}

// ---------------- launch ----------------
extern "C" void kernel_launch(void* const* d_in, const int* in_sizes, int n_in,
                              void* d_out, int out_size, void* d_ws, size_t ws_size,
                              hipStream_t stream)
{
    const float* gene_emb = (const float*)d_in[0];
    const float* expr_emb = (const float*)d_in[1];
    const float* M        = (const float*)d_in[2];
    const float* g_wq = (const float*)d_in[3];
    const float* g_wk = (const float*)d_in[4];
    const float* g_wv = (const float*)d_in[5];
    const float* g_wo = (const float*)d_in[6];
    const float* g_bq = (const float*)d_in[7];
    const float* g_bk = (const float*)d_in[8];
    const float* g_bv = (const float*)d_in[9];
    const float* g_bo = (const float*)d_in[10];
    const float* e_wf = (const float*)d_in[11];
    const float* e_bf = (const float*)d_in[12];
    const float* e_wq = (const float*)d_in[13];
    const float* e_wk = (const float*)d_in[14];
    const float* e_wv = (const float*)d_in[15];
    const float* e_wo = (const float*)d_in[16];
    const float* e_bq = (const float*)d_in[17];
    const float* e_bk = (const float*)d_in[18];
    const float* e_bv = (const float*)d_in[19];
    const float* e_bo = (const float*)d_in[20];
    const float* ln_g1_w = (const float*)d_in[21];
    const float* ln_g2_w = (const float*)d_in[22];
    const float* ln_e1_w = (const float*)d_in[23];
    const float* ln_e2_w = (const float*)d_in[24];
    const float* ln_g1_b = (const float*)d_in[25];
    const float* ln_g2_b = (const float*)d_in[26];
    const float* ln_e1_b = (const float*)d_in[27];
    const float* ln_e2_b = (const float*)d_in[28];
    const float* fg_w1 = (const float*)d_in[29];
    const float* fg_b1 = (const float*)d_in[30];
    const float* fg_w2 = (const float*)d_in[31];
    const float* fg_b2 = (const float*)d_in[32];
    const float* fe_w1 = (const float*)d_in[33];
    const float* fe_b1 = (const float*)d_in[34];
    const float* fe_w2 = (const float*)d_in[35];
    const float* fe_b2 = (const float*)d_in[36];

    float* out_gene = (float*)d_out;
    float* out_expr = out_gene + (size_t)NROWS * DMODEL;

    // ---- workspace (MB offsets), peak ~54.2 MB ----
    char* ws = (char*)d_ws;
    const size_t MB1 = 1024 * 1024;
    unsigned short* bufA16  = (unsigned short*)(ws + 0 * MB1);   // 0-4
    unsigned short* bufAt16 = (unsigned short*)(ws + 4 * MB1);   // 4-8 attn combined
    unsigned short* bufQKV  = (unsigned short*)(ws + 8 * MB1);   // 8-20 gene [4096][1536]
    unsigned short* bufQKe  = (unsigned short*)(ws + 8 * MB1);   // 8-16 expr [4096][1024]
    unsigned short* bufV16  = (unsigned short*)(ws + 16 * MB1);  // 16-20 expr V
    unsigned short* bufVt   = (unsigned short*)(ws + 20 * MB1);  // 20-24
    unsigned short* bufCat  = (unsigned short*)(ws + 24 * MB1);  // 24-32 expr concat (dead pre-attn)
    unsigned short* bufOp   = (unsigned short*)(ws + 24 * MB1);  // 24-32 attn O partials
    float*          bufSt   = (float*)(ws + 32 * MB1);           // 32-33 attn stats
    float*          bufX    = (float*)(ws + 33 * MB1);           // 33-41 fp32 residual
    unsigned short* bufH16  = (unsigned short*)(ws + 8 * MB1);   // 8-24 FFN hidden
    // weights: 8 square (4MB) | ewf (1MB) | ffn1 pair (4MB) | ffn2 pair (4MB)
    char* wp = ws + 41 * MB1;
    unsigned short* sq8    = (unsigned short*)wp;                 // 8 x 512x512
    unsigned short* gwq_t  = sq8 + 0 * 512 * 512;
    unsigned short* gwk_t  = sq8 + 1 * 512 * 512;
    unsigned short* gwv_t  = sq8 + 2 * 512 * 512;
    unsigned short* gwo_t  = sq8 + 3 * 512 * 512;
    unsigned short* ewq_t  = sq8 + 4 * 512 * 512;
    unsigned short* ewk_t  = sq8 + 5 * 512 * 512;
    unsigned short* ewv_t  = sq8 + 6 * 512 * 512;
    unsigned short* ewo_t  = sq8 + 7 * 512 * 512;
    unsigned short* ewf_t  = sq8 + 8 * 512 * 512;                 // 1024x512
    unsigned short* ffn1   = ewf_t + 1024 * 512;                  // 2 x [2048][512]
    unsigned short* fgw1_t = ffn1;
    unsigned short* few1_t = ffn1 + 512 * 2048;
    unsigned short* ffn2   = few1_t + 512 * 2048;                 // 2 x [512][2048]
    unsigned short* fgw2_t = ffn2;
    unsigned short* few2_t = ffn2 + 2048 * 512;
    float* biasg = (float*)(few2_t + 2048 * 512);
    float* biase = biasg + 1536;

    dim3 blk(256);
    dim3 ln_grid(NROWS);
    dim3 g512s(8, 64);    // 64x64 tiles, Mo=512 -> 512 blocks
    dim3 g1024(8, 32);
    dim3 g1536(12, 32);
    dim3 g2048(16, 32);
    dim3 attn_grid(S_LEN / 64, 16, 2);
    dim3 comb_grid(S_LEN / 64, 16);
    dim3 vt_grid(S_LEN / 64, NHEAD, 2);

    // ---- weight prep (4 launches) ----
    wcast_sq8<<<dim3(16, 16, 8), blk, 0, stream>>>(
        g_wq, g_wk, g_wv, g_wo, e_wq, e_wk, e_wv, e_wo, sq8);
    wcast_t<<<dim3(16, 32), blk, 0, stream>>>(e_wf, ewf_t, 1024, 512);
    wcast_t2<<<dim3(64, 16, 2), blk, 0, stream>>>(fg_w1, fe_w1, ffn1, 512, 2048);
    wcast_t2<<<dim3(16, 64, 2), blk, 0, stream>>>(fg_w2, fe_w2, ffn2, 2048, 512);
    pack_bias<<<dim3(6), blk, 0, stream>>>(g_bq, g_bk, g_bv, biasg, 1536);
    pack_bias<<<dim3(4), blk, 0, stream>>>(e_bq, e_bk, e_bk, biase, 1024);

    // ---------------- gene branch ----------------
    ln_kernel<<<ln_grid, blk, 0, stream>>>(gene_emb, ln_g1_w, ln_g1_b, bufA16, 512);
    gemm_mfma<<<g1536, blk, 0, stream>>>(bufA16, 512, gwq_t, biasg, nullptr, nullptr, nullptr, bufQKV, 512, 1536, 0);
    vtrans<<<vt_grid, blk, 0, stream>>>(bufQKV + 1024, 1536, bufVt);
    attn_mfma_split<<<attn_grid, blk, 0, stream>>>(bufQKV, 1536, bufQKV + 512, 1536, bufVt, M, bufOp, bufSt);
    attn_combine<<<comb_grid, blk, 0, stream>>>(bufOp, bufSt, bufAt16);
    gemm_mfma64<<<g512s, blk, 0, stream>>>(bufAt16, 512, gwo_t, g_bo, gene_emb, nullptr, bufX, nullptr, 512, 512, 0);
    ln_kernel<<<ln_grid, blk, 0, stream>>>(bufX, ln_g2_w, ln_g2_b, bufA16, 512);
    gemm_mfma<<<g2048, blk, 0, stream>>>(bufA16, 512, fgw1_t, fg_b1, nullptr, nullptr, nullptr, bufH16, 512, 2048, 1);
    gemm_mfma64<<<g512s, blk, 0, stream>>>(bufH16, 2048, fgw2_t, fg_b2, bufX, bufA16, out_gene, nullptr, 2048, 512, 0);

    // ---------------- expr branch ----------------
    cast_strided<<<ln_grid, blk, 0, stream>>>(gene_emb, bufCat, 1024);
    ln_kernel<<<ln_grid, blk, 0, stream>>>(expr_emb, ln_e1_w, ln_e1_b, bufCat + 512, 1024);
    gemm_mfma64<<<g512s, blk, 0, stream>>>(bufCat, 1024, ewf_t, e_bf, nullptr, nullptr, nullptr, bufA16, 1024, 512, 0);
    gemm_mfma<<<g1024, blk, 0, stream>>>(bufA16, 512, ewq_t, biase, nullptr, nullptr, nullptr, bufQKe, 512, 1024, 0);
    gemm_mfma64<<<g512s, blk, 0, stream>>>(bufCat + 512, 1024, ewv_t, e_bv, nullptr, nullptr, nullptr, bufV16, 512, 512, 0);
    vtrans<<<vt_grid, blk, 0, stream>>>(bufV16, 512, bufVt);
    attn_mfma_split<<<attn_grid, blk, 0, stream>>>(bufQKe, 1024, bufQKe + 512, 1024, bufVt, M, bufOp, bufSt);
    attn_combine<<<comb_grid, blk, 0, stream>>>(bufOp, bufSt, bufAt16);
    gemm_mfma64<<<g512s, blk, 0, stream>>>(bufAt16, 512, ewo_t, e_bo, expr_emb, nullptr, bufX, nullptr, 512, 512, 0);
    ln_kernel<<<ln_grid, blk, 0, stream>>>(bufX, ln_e2_w, ln_e2_b, bufA16, 512);
    gemm_mfma<<<g2048, blk, 0, stream>>>(bufA16, 512, few1_t, fe_b1, nullptr, nullptr, nullptr, bufH16, 512, 2048, 1);
    gemm_mfma64<<<g512s, blk, 0, stream>>>(bufH16, 2048, few2_t, fe_b2, bufX, bufA16, out_expr, nullptr, 2048, 512, 0);
}

// Round 7
// 545.456 us; speedup vs baseline: 15.2520x; 1.0311x over previous
//
#include <hip/hip_runtime.h>
#include <math.h>

// Problem constants
#define S_LEN 2048
#define DMODEL 512
#define NROWS 4096   // B*S
#define NHEAD 8
#define HDIM 64

typedef __attribute__((ext_vector_type(8))) __bf16 bf16x8;
typedef __attribute__((ext_vector_type(4))) float f32x4;

__device__ inline float bf2f(unsigned short h) {
    unsigned u = ((unsigned)h) << 16;
    return __builtin_bit_cast(float, u);
}
__device__ inline unsigned short f2bf(float f) {
    unsigned u = __builtin_bit_cast(unsigned, f);
    return (unsigned short)((u + 0x7fffu + ((u >> 16) & 1u)) >> 16);
}

// async global->LDS, 16B per lane; LDS dest = wave-uniform base + lane*16
__device__ inline void gl_lds16(const unsigned short* g, unsigned short* l) {
    __builtin_amdgcn_global_load_lds(
        (const __attribute__((address_space(1))) void*)g,
        (__attribute__((address_space(3))) void*)l, 16, 0, 0);
}

// ---------------- weight cast + transpose: Wt[mo][k] = bf16(W[k][mo]) ------
__global__ __launch_bounds__(256) void wcast_t(
    const float* __restrict__ W, unsigned short* __restrict__ Wt, int K, int Mo)
{
    __shared__ float t[32][33];
    const int bx = blockIdx.x * 32;   // Mo
    const int by = blockIdx.y * 32;   // K
    const int tx = threadIdx.x & 31, ty = threadIdx.x >> 5;
    #pragma unroll
    for (int r = 0; r < 4; ++r)
        t[ty + 8 * r][tx] = W[(size_t)(by + ty + 8 * r) * Mo + bx + tx];
    __syncthreads();
    #pragma unroll
    for (int r = 0; r < 4; ++r)
        Wt[(size_t)(bx + ty + 8 * r) * K + by + tx] = f2bf(t[tx][ty + 8 * r]);
}

// 8 square 512x512 weights in one launch (blockIdx.z selects)
__global__ __launch_bounds__(256) void wcast_sq8(
    const float* w0, const float* w1, const float* w2, const float* w3,
    const float* w4, const float* w5, const float* w6, const float* w7,
    unsigned short* __restrict__ dst)
{
    const float* srcs[8] = {w0, w1, w2, w3, w4, w5, w6, w7};
    const float* __restrict__ W = srcs[blockIdx.z];
    unsigned short* __restrict__ Wt = dst + (size_t)blockIdx.z * 512 * 512;
    __shared__ float t[32][33];
    const int bx = blockIdx.x * 32, by = blockIdx.y * 32;
    const int tx = threadIdx.x & 31, ty = threadIdx.x >> 5;
    #pragma unroll
    for (int r = 0; r < 4; ++r)
        t[ty + 8 * r][tx] = W[(size_t)(by + ty + 8 * r) * 512 + bx + tx];
    __syncthreads();
    #pragma unroll
    for (int r = 0; r < 4; ++r)
        Wt[(size_t)(bx + ty + 8 * r) * 512 + by + tx] = f2bf(t[tx][ty + 8 * r]);
}

// pair of same-shape weights in one launch (dst contiguous, stride K*Mo)
__global__ __launch_bounds__(256) void wcast_t2(
    const float* wA, const float* wB, unsigned short* __restrict__ dst,
    int K, int Mo)
{
    const float* __restrict__ W = blockIdx.z ? wB : wA;
    unsigned short* __restrict__ Wt = dst + (size_t)blockIdx.z * K * Mo;
    __shared__ float t[32][33];
    const int bx = blockIdx.x * 32, by = blockIdx.y * 32;
    const int tx = threadIdx.x & 31, ty = threadIdx.x >> 5;
    #pragma unroll
    for (int r = 0; r < 4; ++r)
        t[ty + 8 * r][tx] = W[(size_t)(by + ty + 8 * r) * Mo + bx + tx];
    __syncthreads();
    #pragma unroll
    for (int r = 0; r < 4; ++r)
        Wt[(size_t)(bx + ty + 8 * r) * K + by + tx] = f2bf(t[tx][ty + 8 * r]);
}

// ---------------- pack up to 3 bias vectors (512 each) into one ----------
__global__ __launch_bounds__(256) void pack_bias(
    const float* __restrict__ b1, const float* __restrict__ b2,
    const float* __restrict__ b3, float* __restrict__ dst, int n)
{
    int t = blockIdx.x * 256 + threadIdx.x;
    if (t >= n) return;
    float v = (t < 512) ? b1[t] : (t < 1024) ? b2[t - 512] : b3[t - 1024];
    dst[t] = v;
}

// ---------------- strided fp32 -> bf16 cast (gene_emb -> concat left) ------
__global__ __launch_bounds__(256) void cast_strided(
    const float* __restrict__ in, unsigned short* __restrict__ out, int ostride)
{
    const int row = blockIdx.x, t = threadIdx.x;
    out[(size_t)row * ostride + t]       = f2bf(in[(size_t)row * DMODEL + t]);
    out[(size_t)row * ostride + t + 256] = f2bf(in[(size_t)row * DMODEL + t + 256]);
}

// ---------------- LayerNorm: fp32 in, bf16 out (strided) ----------------
__global__ __launch_bounds__(256) void ln_kernel(
    const float* __restrict__ x, const float* __restrict__ w,
    const float* __restrict__ b, unsigned short* __restrict__ y, int ostride)
{
    __shared__ float red[8];
    const int row = blockIdx.x;
    const float* xr = x + (size_t)row * DMODEL;
    const int t = threadIdx.x;
    float v0 = xr[t];
    float v1 = xr[t + 256];
    float s  = v0 + v1;
    float sq = v0 * v0 + v1 * v1;
    #pragma unroll
    for (int o = 32; o > 0; o >>= 1) {
        s  += __shfl_down(s, o);
        sq += __shfl_down(sq, o);
    }
    int wid = t >> 6, lane = t & 63;
    if (lane == 0) { red[wid] = s; red[4 + wid] = sq; }
    __syncthreads();
    float mean = (red[0] + red[1] + red[2] + red[3]) * (1.0f / 512.0f);
    float msq  = (red[4] + red[5] + red[6] + red[7]) * (1.0f / 512.0f);
    float var  = msq - mean * mean;
    float rs   = rsqrtf(var + 1e-5f);
    y[(size_t)row * ostride + t]       = f2bf((v0 - mean) * rs * w[t] + b[t]);
    y[(size_t)row * ostride + t + 256] = f2bf((v1 - mean) * rs * w[t + 256] + b[t + 256]);
}

// ---------------- V transpose: Vt[(b*8+h)*64 + d][s] = V[b*2048+s][h*64+d] --
__global__ __launch_bounds__(256) void vtrans(
    const unsigned short* __restrict__ V, int ldv, unsigned short* __restrict__ Vt)
{
    __shared__ unsigned short t[64][72];
    const int s0 = blockIdx.x * 64, h = blockIdx.y, b = blockIdx.z;
    const int tid = threadIdx.x;
    {
        const int r = tid >> 2, c = (tid & 3) * 16;
        const unsigned short* src = V + (size_t)(b * S_LEN + s0 + r) * ldv + h * 64 + c;
        *(int4*)&t[r][c]     = *(const int4*)(src);
        *(int4*)&t[r][c + 8] = *(const int4*)(src + 8);
    }
    __syncthreads();
    {
        const int d = tid >> 2, s = (tid & 3) * 16;
        unsigned short* dst = Vt + ((size_t)((b * 8 + h) * 64 + d)) * S_LEN + s0 + s;
        unsigned short tmp[16];
        #pragma unroll
        for (int e = 0; e < 16; ++e) tmp[e] = t[s + e][d];
        *(int4*)dst       = *(int4*)&tmp[0];
        *(int4*)(dst + 8) = *(int4*)&tmp[8];
    }
}

// ---------------- bf16 MFMA GEMM, 128x128 tile, BK=32, async staging -------
__global__ __launch_bounds__(256) void gemm_mfma(
    const unsigned short* __restrict__ A, int lda,
    const unsigned short* __restrict__ Bt,
    const float* __restrict__ bias,
    const float* __restrict__ R1,
    const unsigned short* __restrict__ R2,
    float* __restrict__ Cf, unsigned short* __restrict__ Cb,
    int K, int Mo, int dogelu)
{
    __shared__ __align__(16) unsigned short As[128 * 32];
    __shared__ __align__(16) unsigned short Bs[128 * 32];
    const int tid = threadIdx.x;
    const int wave = tid >> 6, lane = tid & 63;
    const int wr = wave >> 1, wc = wave & 1;
    const int row0 = blockIdx.y * 128, col0 = blockIdx.x * 128;
    const int l15 = lane & 15, q = lane >> 4;

    f32x4 acc[4][4];
    const f32x4 zz = {0.f, 0.f, 0.f, 0.f};
    #pragma unroll
    for (int i = 0; i < 4; ++i)
        #pragma unroll
        for (int j = 0; j < 4; ++j) acc[i][j] = zz;

    for (int k0 = 0; k0 < K; k0 += 32) {
        // slot idx -> LDS byte offset idx*16 (contiguous in tid): wave-uniform
        // base + lane*16 matches global_load_lds semantics.
        #pragma unroll
        for (int r = 0; r < 2; ++r) {
            int idx = r * 256 + tid;
            int row = idx >> 2, kc = idx & 3;
            gl_lds16(&A[(size_t)(row0 + row) * lda + k0 + kc * 8],
                     &As[(size_t)(r * 256 + wave * 64) * 8]);
            gl_lds16(&Bt[(size_t)(col0 + row) * K + k0 + kc * 8],
                     &Bs[(size_t)(r * 256 + wave * 64) * 8]);
        }
        __syncthreads();
        bf16x8 af[4], bfr[4];
        #pragma unroll
        for (int fi = 0; fi < 4; ++fi)
            af[fi] = *(const bf16x8*)&As[(wr * 64 + fi * 16 + l15) * 32 + q * 8];
        #pragma unroll
        for (int fj = 0; fj < 4; ++fj)
            bfr[fj] = *(const bf16x8*)&Bs[(wc * 64 + fj * 16 + l15) * 32 + q * 8];
        #pragma unroll
        for (int fi = 0; fi < 4; ++fi)
            #pragma unroll
            for (int fj = 0; fj < 4; ++fj)
                acc[fi][fj] = __builtin_amdgcn_mfma_f32_16x16x32_bf16(
                    af[fi], bfr[fj], acc[fi][fj], 0, 0, 0);
        __syncthreads();
    }

    #pragma unroll
    for (int fi = 0; fi < 4; ++fi) {
        #pragma unroll
        for (int reg = 0; reg < 4; ++reg) {
            int row = row0 + wr * 64 + fi * 16 + q * 4 + reg;
            #pragma unroll
            for (int fj = 0; fj < 4; ++fj) {
                int col = col0 + wc * 64 + fj * 16 + l15;
                float v = acc[fi][fj][reg] + bias[col];
                if (dogelu) v = 0.5f * v * (1.0f + erff(v * 0.70710678118654752f));
                size_t off = (size_t)row * Mo + col;
                if (R1) v += R1[off];
                if (R2) v += bf2f(R2[off]);
                if (Cb) Cb[off] = f2bf(v);
                else    Cf[off] = v;
            }
        }
    }
}

// ---------------- bf16 MFMA GEMM, 64x64 tile, BK=64, async staging ---------
__global__ __launch_bounds__(256) void gemm_mfma64(
    const unsigned short* __restrict__ A, int lda,
    const unsigned short* __restrict__ Bt,
    const float* __restrict__ bias,
    const float* __restrict__ R1,
    const unsigned short* __restrict__ R2,
    float* __restrict__ Cf, unsigned short* __restrict__ Cb,
    int K, int Mo, int dogelu)
{
    __shared__ __align__(16) unsigned short As[64 * 64];
    __shared__ __align__(16) unsigned short Bs[64 * 64];
    const int tid = threadIdx.x;
    const int wave = tid >> 6, lane = tid & 63;
    const int row0 = blockIdx.y * 64, col0 = blockIdx.x * 64;
    const int l15 = lane & 15, q = lane >> 4;

    f32x4 acc[4];
    const f32x4 zz = {0.f, 0.f, 0.f, 0.f};
    #pragma unroll
    for (int j = 0; j < 4; ++j) acc[j] = zz;

    for (int k0 = 0; k0 < K; k0 += 64) {
        // 64x64 shorts = 8 KB per matrix; slot idx -> byte offset idx*16
        #pragma unroll
        for (int r = 0; r < 2; ++r) {
            int idx = r * 256 + tid;
            int row = idx >> 3, kc = idx & 7;
            gl_lds16(&A[(size_t)(row0 + row) * lda + k0 + kc * 8],
                     &As[(size_t)(r * 256 + wave * 64) * 8]);
            gl_lds16(&Bt[(size_t)(col0 + row) * K + k0 + kc * 8],
                     &Bs[(size_t)(r * 256 + wave * 64) * 8]);
        }
        __syncthreads();
        #pragma unroll
        for (int ks = 0; ks < 2; ++ks) {
            bf16x8 af = *(const bf16x8*)&As[(wave * 16 + l15) * 64 + ks * 32 + q * 8];
            bf16x8 bfr[4];
            #pragma unroll
            for (int fj = 0; fj < 4; ++fj)
                bfr[fj] = *(const bf16x8*)&Bs[(fj * 16 + l15) * 64 + ks * 32 + q * 8];
            #pragma unroll
            for (int fj = 0; fj < 4; ++fj)
                acc[fj] = __builtin_amdgcn_mfma_f32_16x16x32_bf16(af, bfr[fj], acc[fj], 0, 0, 0);
        }
        __syncthreads();
    }

    #pragma unroll
    for (int reg = 0; reg < 4; ++reg) {
        int row = row0 + wave * 16 + q * 4 + reg;
        #pragma unroll
        for (int fj = 0; fj < 4; ++fj) {
            int col = col0 + fj * 16 + l15;
            float v = acc[fj][reg] + bias[col];
            if (dogelu) v = 0.5f * v * (1.0f + erff(v * 0.70710678118654752f));
            size_t off = (size_t)row * Mo + col;
            if (R1) v += R1[off];
            if (R2) v += bf2f(R2[off]);
            if (Cb) Cb[off] = f2bf(v);
            else    Cf[off] = v;
        }
    }
}

// ---------------- MFMA flash attention, split-K, LDS-staged tiles ----------
__global__ __launch_bounds__(256, 4) void attn_mfma_split(
    const unsigned short* __restrict__ Q, int ldq,
    const unsigned short* __restrict__ Kp, int ldk,
    const unsigned short* __restrict__ Vt,   // [16 bh][64 d][2048 s]
    const float* __restrict__ M,
    unsigned short* __restrict__ Opart,      // [2][16][2048][64] bf16
    float* __restrict__ stats)               // [2][16][2048][4] f32
{
    __shared__ __align__(16) unsigned short Ks[64 * 72];
    __shared__ __align__(16) unsigned short Vs[64 * 72];
    __shared__ __align__(16) float Ms[4][16 * 68];   // per-wave M; P aliases

    const int bh = blockIdx.y, b = bh >> 3, h = bh & 7;
    const int q0 = blockIdx.x * 64;
    const int p = blockIdx.z;
    const int tid = threadIdx.x, wave = tid >> 6, lane = tid & 63;
    const int l15 = lane & 15, quad = lane >> 4;
    const int iRow = q0 + wave * 16 + l15;
    const int kBeg = p * (S_LEN / 2), kEnd = kBeg + (S_LEN / 2);

    unsigned short* Ps = (unsigned short*)&Ms[wave][0];   // [16][72] shorts

    bf16x8 qf[2];
    {
        const unsigned short* qp = Q + (size_t)(b * S_LEN + iRow) * ldq + h * HDIM + quad * 8;
        #pragma unroll
        for (int ks = 0; ks < 2; ++ks) {
            union { bf16x8 v; unsigned short u[8]; } tq;
            tq.v = *(const bf16x8*)(qp + ks * 32);
            #pragma unroll
            for (int e = 0; e < 8; ++e) tq.u[e] = f2bf(bf2f(tq.u[e]) * 0.125f);
            qf[ks] = tq.v;
        }
    }

    float rm = -INFINITY, rZ = 0.f, rZm = 0.f;
    f32x4 oacc[4];
    const f32x4 zz = {0.f, 0.f, 0.f, 0.f};
    #pragma unroll
    for (int dt = 0; dt < 4; ++dt) oacc[dt] = zz;

    const int srow = tid >> 3;            // 0..31
    const int scol = (tid & 7) * 8;       // 0..56 shorts
    const unsigned short* kg = Kp + ((size_t)b * S_LEN) * ldk + h * HDIM + scol;
    const unsigned short* vg = Vt + ((size_t)bh * 64 + srow) * S_LEN + scol;
    const float* mg = M + (size_t)b * S_LEN * S_LEN + (size_t)(q0 + wave * 16) * S_LEN;

    for (int k0 = kBeg; k0 < kEnd; k0 += 64) {
        __syncthreads();
        int4 kv0 = *(const int4*)(kg + (size_t)(k0 + srow) * ldk);
        int4 kv1 = *(const int4*)(kg + (size_t)(k0 + srow + 32) * ldk);
        int4 vv0 = *(const int4*)(vg + k0);
        int4 vv1 = *(const int4*)(vg + 32 * S_LEN + k0);
        float4 mv[4];
        #pragma unroll
        for (int c = 0; c < 4; ++c)
            mv[c] = *(const float4*)(mg + (size_t)(c * 4 + quad) * S_LEN + k0 + l15 * 4);
        *(int4*)&Ks[srow * 72 + scol]        = kv0;
        *(int4*)&Ks[(srow + 32) * 72 + scol] = kv1;
        *(int4*)&Vs[srow * 72 + scol]        = vv0;
        *(int4*)&Vs[(srow + 32) * 72 + scol] = vv1;
        #pragma unroll
        for (int c = 0; c < 4; ++c)
            *(float4*)&Ms[wave][(c * 4 + quad) * 68 + l15 * 4] = mv[c];
        __syncthreads();

        float4 m4[4];
        #pragma unroll
        for (int jt = 0; jt < 4; ++jt)
            m4[jt] = *(const float4*)&Ms[wave][l15 * 68 + jt * 16 + quad * 4];

        f32x4 sacc[4];
        #pragma unroll
        for (int jt = 0; jt < 4; ++jt) sacc[jt] = zz;
        #pragma unroll
        for (int jt = 0; jt < 4; ++jt) {
            bf16x8 kf0 = *(const bf16x8*)&Ks[(jt * 16 + l15) * 72 + quad * 8];
            bf16x8 kf1 = *(const bf16x8*)&Ks[(jt * 16 + l15) * 72 + 32 + quad * 8];
            sacc[jt] = __builtin_amdgcn_mfma_f32_16x16x32_bf16(kf0, qf[0], sacc[jt], 0, 0, 0);
            sacc[jt] = __builtin_amdgcn_mfma_f32_16x16x32_bf16(kf1, qf[1], sacc[jt], 0, 0, 0);
        }

        float mx = -INFINITY;
        #pragma unroll
        for (int jt = 0; jt < 4; ++jt) {
            float mm[4] = {m4[jt].x, m4[jt].y, m4[jt].z, m4[jt].w};
            #pragma unroll
            for (int r = 0; r < 4; ++r) {
                sacc[jt][r] = sacc[jt][r] * mm[r];
                mx = fmaxf(mx, sacc[jt][r]);
            }
        }
        mx = fmaxf(mx, __shfl_xor(mx, 16));
        mx = fmaxf(mx, __shfl_xor(mx, 32));
        float mn = fmaxf(rm, mx);
        float al = __expf(rm - mn);
        rm = mn; rZ *= al; rZm *= al;
        #pragma unroll
        for (int dt = 0; dt < 4; ++dt)
            #pragma unroll
            for (int r = 0; r < 4; ++r) oacc[dt][r] *= al;

        float z = 0.f, zm = 0.f;
        #pragma unroll
        for (int jt = 0; jt < 4; ++jt) {
            float mm[4] = {m4[jt].x, m4[jt].y, m4[jt].z, m4[jt].w};
            float pv[4];
            #pragma unroll
            for (int r = 0; r < 4; ++r) {
                float e = __expf(sacc[jt][r] - mn);
                float pm = e * mm[r];
                z += e; zm += pm; pv[r] = pm;
            }
            unsigned lo = (unsigned)f2bf(pv[0]) | ((unsigned)f2bf(pv[1]) << 16);
            unsigned hi = (unsigned)f2bf(pv[2]) | ((unsigned)f2bf(pv[3]) << 16);
            uint2 pk; pk.x = lo; pk.y = hi;
            *(uint2*)&Ps[l15 * 72 + jt * 16 + quad * 4] = pk;
        }
        z  += __shfl_xor(z, 16);  z  += __shfl_xor(z, 32);
        zm += __shfl_xor(zm, 16); zm += __shfl_xor(zm, 32);
        rZ += z; rZm += zm;

        bf16x8 pf0 = *(const bf16x8*)&Ps[l15 * 72 + quad * 8];
        bf16x8 pf1 = *(const bf16x8*)&Ps[l15 * 72 + 32 + quad * 8];
        #pragma unroll
        for (int dt = 0; dt < 4; ++dt) {
            bf16x8 vf0 = *(const bf16x8*)&Vs[(dt * 16 + l15) * 72 + quad * 8];
            bf16x8 vf1 = *(const bf16x8*)&Vs[(dt * 16 + l15) * 72 + 32 + quad * 8];
            oacc[dt] = __builtin_amdgcn_mfma_f32_16x16x32_bf16(vf0, pf0, oacc[dt], 0, 0, 0);
            oacc[dt] = __builtin_amdgcn_mfma_f32_16x16x32_bf16(vf1, pf1, oacc[dt], 0, 0, 0);
        }
    }

    unsigned short* op = Opart + (((size_t)(p * 16 + bh) * S_LEN + iRow) * 64);
    #pragma unroll
    for (int dt = 0; dt < 4; ++dt) {
        ushort4 o4;
        o4.x = f2bf(oacc[dt][0]); o4.y = f2bf(oacc[dt][1]);
        o4.z = f2bf(oacc[dt][2]); o4.w = f2bf(oacc[dt][3]);
        *(ushort4*)(op + dt * 16 + quad * 4) = o4;
    }
    if (quad == 0) {
        float4 st; st.x = rm; st.y = rZ; st.z = rZm; st.w = 0.f;
        *(float4*)&stats[(((size_t)p * 16 + bh) * S_LEN + iRow) * 4] = st;
    }
}

// ---------------- combine the two split-K partials ----------------
__global__ __launch_bounds__(256) void attn_combine(
    const unsigned short* __restrict__ Opart, const float* __restrict__ stats,
    unsigned short* __restrict__ O)
{
    const int bh = blockIdx.y, b = bh >> 3, h = bh & 7;
    const int q0 = blockIdx.x * 64;
    const int tid = threadIdx.x;
    const int i = tid >> 2, dq = (tid & 3) * 16;
    const int qg = q0 + i;

    float4 s0 = *(const float4*)&stats[(((size_t)0 * 16 + bh) * S_LEN + qg) * 4];
    float4 s1 = *(const float4*)&stats[(((size_t)1 * 16 + bh) * S_LEN + qg) * 4];
    float ms = fmaxf(s0.x, s1.x);
    float w0 = __expf(s0.x - ms), w1 = __expf(s1.x - ms);
    float Z  = w0 * s0.y + w1 * s1.y;
    float Zm = w0 * s0.z + w1 * s1.z;
    float inv = 1.0f / (Zm + 1e-8f * Z);
    w0 *= inv; w1 *= inv;

    const unsigned short* p0 = Opart + (((size_t)0 * 16 + bh) * S_LEN + qg) * 64 + dq;
    const unsigned short* p1 = Opart + (((size_t)1 * 16 + bh) * S_LEN + qg) * 64 + dq;
    union { int4 v; unsigned short u[8]; } a0, a1, r;
    unsigned short* dst = O + (size_t)(b * S_LEN + qg) * DMODEL + h * HDIM + dq;
    #pragma unroll
    for (int half = 0; half < 2; ++half) {
        a0.v = *(const int4*)(p0 + half * 8);
        a1.v = *(const int4*)(p1 + half * 8);
        #pragma unroll
        for (int e = 0; e < 8; ++e)
            r.u[e] = f2bf(w0 * bf2f(a0.u[e]) + w1 * bf2f(a1.u[e]));
        *(int4*)(dst + half * 8) = r.v;
    }
}

// ---------------- launch ----------------
extern "C" void kernel_launch(void* const* d_in, const int* in_sizes, int n_in,
                              void* d_out, int out_size, void* d_ws, size_t ws_size,
                              hipStream_t stream)
{
    const float* gene_emb = (const float*)d_in[0];
    const float* expr_emb = (const float*)d_in[1];
    const float* M        = (const float*)d_in[2];
    const float* g_wq = (const float*)d_in[3];
    const float* g_wk = (const float*)d_in[4];
    const float* g_wv = (const float*)d_in[5];
    const float* g_wo = (const float*)d_in[6];
    const float* g_bq = (const float*)d_in[7];
    const float* g_bk = (const float*)d_in[8];
    const float* g_bv = (const float*)d_in[9];
    const float* g_bo = (const float*)d_in[10];
    const float* e_wf = (const float*)d_in[11];
    const float* e_bf = (const float*)d_in[12];
    const float* e_wq = (const float*)d_in[13];
    const float* e_wk = (const float*)d_in[14];
    const float* e_wv = (const float*)d_in[15];
    const float* e_wo = (const float*)d_in[16];
    const float* e_bq = (const float*)d_in[17];
    const float* e_bk = (const float*)d_in[18];
    const float* e_bv = (const float*)d_in[19];
    const float* e_bo = (const float*)d_in[20];
    const float* ln_g1_w = (const float*)d_in[21];
    const float* ln_g2_w = (const float*)d_in[22];
    const float* ln_e1_w = (const float*)d_in[23];
    const float* ln_e2_w = (const float*)d_in[24];
    const float* ln_g1_b = (const float*)d_in[25];
    const float* ln_g2_b = (const float*)d_in[26];
    const float* ln_e1_b = (const float*)d_in[27];
    const float* ln_e2_b = (const float*)d_in[28];
    const float* fg_w1 = (const float*)d_in[29];
    const float* fg_b1 = (const float*)d_in[30];
    const float* fg_w2 = (const float*)d_in[31];
    const float* fg_b2 = (const float*)d_in[32];
    const float* fe_w1 = (const float*)d_in[33];
    const float* fe_b1 = (const float*)d_in[34];
    const float* fe_w2 = (const float*)d_in[35];
    const float* fe_b2 = (const float*)d_in[36];

    float* out_gene = (float*)d_out;
    float* out_expr = out_gene + (size_t)NROWS * DMODEL;

    // ---- workspace (MB offsets), peak ~54.2 MB ----
    char* ws = (char*)d_ws;
    const size_t MB1 = 1024 * 1024;
    unsigned short* bufA16  = (unsigned short*)(ws + 0 * MB1);   // 0-4
    unsigned short* bufAt16 = (unsigned short*)(ws + 4 * MB1);   // 4-8 attn combined
    unsigned short* bufQKV  = (unsigned short*)(ws + 8 * MB1);   // 8-20 gene [4096][1536]
    unsigned short* bufQKe  = (unsigned short*)(ws + 8 * MB1);   // 8-16 expr [4096][1024]
    unsigned short* bufV16  = (unsigned short*)(ws + 16 * MB1);  // 16-20 expr V
    unsigned short* bufVt   = (unsigned short*)(ws + 20 * MB1);  // 20-24
    unsigned short* bufCat  = (unsigned short*)(ws + 24 * MB1);  // 24-32 expr concat (dead pre-attn)
    unsigned short* bufOp   = (unsigned short*)(ws + 24 * MB1);  // 24-32 attn O partials
    float*          bufSt   = (float*)(ws + 32 * MB1);           // 32-33 attn stats
    float*          bufX    = (float*)(ws + 33 * MB1);           // 33-41 fp32 residual
    unsigned short* bufH16  = (unsigned short*)(ws + 8 * MB1);   // 8-24 FFN hidden
    char* wp = ws + 41 * MB1;
    unsigned short* sq8    = (unsigned short*)wp;                 // 8 x 512x512
    unsigned short* gwq_t  = sq8 + 0 * 512 * 512;
    unsigned short* gwk_t  = sq8 + 1 * 512 * 512;
    unsigned short* gwv_t  = sq8 + 2 * 512 * 512;
    unsigned short* gwo_t  = sq8 + 3 * 512 * 512;
    unsigned short* ewq_t  = sq8 + 4 * 512 * 512;
    unsigned short* ewk_t  = sq8 + 5 * 512 * 512;
    unsigned short* ewv_t  = sq8 + 6 * 512 * 512;
    unsigned short* ewo_t  = sq8 + 7 * 512 * 512;
    unsigned short* ewf_t  = sq8 + 8 * 512 * 512;                 // 1024x512
    unsigned short* ffn1   = ewf_t + 1024 * 512;                  // 2 x [2048][512]
    unsigned short* fgw1_t = ffn1;
    unsigned short* few1_t = ffn1 + 512 * 2048;
    unsigned short* ffn2   = few1_t + 512 * 2048;                 // 2 x [512][2048]
    unsigned short* fgw2_t = ffn2;
    unsigned short* few2_t = ffn2 + 2048 * 512;
    float* biasg = (float*)(few2_t + 2048 * 512);
    float* biase = biasg + 1536;

    dim3 blk(256);
    dim3 ln_grid(NROWS);
    dim3 g512s(8, 64);    // 64x64 tiles, Mo=512 -> 512 blocks
    dim3 g1024(8, 32);
    dim3 g1536(12, 32);
    dim3 g2048(16, 32);
    dim3 attn_grid(S_LEN / 64, 16, 2);
    dim3 comb_grid(S_LEN / 64, 16);
    dim3 vt_grid(S_LEN / 64, NHEAD, 2);

    // ---- weight prep ----
    wcast_sq8<<<dim3(16, 16, 8), blk, 0, stream>>>(
        g_wq, g_wk, g_wv, g_wo, e_wq, e_wk, e_wv, e_wo, sq8);
    wcast_t<<<dim3(16, 32), blk, 0, stream>>>(e_wf, ewf_t, 1024, 512);
    wcast_t2<<<dim3(64, 16, 2), blk, 0, stream>>>(fg_w1, fe_w1, ffn1, 512, 2048);
    wcast_t2<<<dim3(16, 64, 2), blk, 0, stream>>>(fg_w2, fe_w2, ffn2, 2048, 512);
    pack_bias<<<dim3(6), blk, 0, stream>>>(g_bq, g_bk, g_bv, biasg, 1536);
    pack_bias<<<dim3(4), blk, 0, stream>>>(e_bq, e_bk, e_bk, biase, 1024);

    // ---------------- gene branch ----------------
    ln_kernel<<<ln_grid, blk, 0, stream>>>(gene_emb, ln_g1_w, ln_g1_b, bufA16, 512);
    gemm_mfma<<<g1536, blk, 0, stream>>>(bufA16, 512, gwq_t, biasg, nullptr, nullptr, nullptr, bufQKV, 512, 1536, 0);
    vtrans<<<vt_grid, blk, 0, stream>>>(bufQKV + 1024, 1536, bufVt);
    attn_mfma_split<<<attn_grid, blk, 0, stream>>>(bufQKV, 1536, bufQKV + 512, 1536, bufVt, M, bufOp, bufSt);
    attn_combine<<<comb_grid, blk, 0, stream>>>(bufOp, bufSt, bufAt16);
    gemm_mfma64<<<g512s, blk, 0, stream>>>(bufAt16, 512, gwo_t, g_bo, gene_emb, nullptr, bufX, nullptr, 512, 512, 0);
    ln_kernel<<<ln_grid, blk, 0, stream>>>(bufX, ln_g2_w, ln_g2_b, bufA16, 512);
    gemm_mfma<<<g2048, blk, 0, stream>>>(bufA16, 512, fgw1_t, fg_b1, nullptr, nullptr, nullptr, bufH16, 512, 2048, 1);
    gemm_mfma64<<<g512s, blk, 0, stream>>>(bufH16, 2048, fgw2_t, fg_b2, bufX, bufA16, out_gene, nullptr, 2048, 512, 0);

    // ---------------- expr branch ----------------
    cast_strided<<<ln_grid, blk, 0, stream>>>(gene_emb, bufCat, 1024);
    ln_kernel<<<ln_grid, blk, 0, stream>>>(expr_emb, ln_e1_w, ln_e1_b, bufCat + 512, 1024);
    gemm_mfma64<<<g512s, blk, 0, stream>>>(bufCat, 1024, ewf_t, e_bf, nullptr, nullptr, nullptr, bufA16, 1024, 512, 0);
    gemm_mfma<<<g1024, blk, 0, stream>>>(bufA16, 512, ewq_t, biase, nullptr, nullptr, nullptr, bufQKe, 512, 1024, 0);
    gemm_mfma64<<<g512s, blk, 0, stream>>>(bufCat + 512, 1024, ewv_t, e_bv, nullptr, nullptr, nullptr, bufV16, 512, 512, 0);
    vtrans<<<vt_grid, blk, 0, stream>>>(bufV16, 512, bufVt);
    attn_mfma_split<<<attn_grid, blk, 0, stream>>>(bufQKe, 1024, bufQKe + 512, 1024, bufVt, M, bufOp, bufSt);
    attn_combine<<<comb_grid, blk, 0, stream>>>(bufOp, bufSt, bufAt16);
    gemm_mfma64<<<g512s, blk, 0, stream>>>(bufAt16, 512, ewo_t, e_bo, expr_emb, nullptr, bufX, nullptr, 512, 512, 0);
    ln_kernel<<<ln_grid, blk, 0, stream>>>(bufX, ln_e2_w, ln_e2_b, bufA16, 512);
    gemm_mfma<<<g2048, blk, 0, stream>>>(bufA16, 512, few1_t, fe_b1, nullptr, nullptr, nullptr, bufH16, 512, 2048, 1);
    gemm_mfma64<<<g512s, blk, 0, stream>>>(bufH16, 2048, few2_t, fe_b2, bufX, bufA16, out_expr, nullptr, 2048, 512, 0);
}